// Round 1
// 394.371 us; speedup vs baseline: 1.0862x; 1.0862x over previous
//
#include <hip/hip_runtime.h>
#include <hip/hip_fp16.h>

// Problem constants
static constexpr int NN   = 50000;
static constexpr int EE   = 800000;
static constexpr int GG   = 256;
static constexpr int NBLK = (NN + 255) / 256;   // 196
static constexpr int PCH  = 16;                 // pooling chunks per graph

// ---------- helpers ----------
__device__ __forceinline__ int lowerb(const int* __restrict__ b, int n, int v) {
    int lo = 0, hi = n;
    while (lo < hi) { int m = (lo + hi) >> 1; if (b[m] < v) lo = m + 1; else hi = m; }
    return lo;
}

// ---------- CSR build (by target node = col) ----------
__global__ void count_k(const int* __restrict__ ei, int* __restrict__ cnt)
{
    int e = blockIdx.x * 256 + threadIdx.x;
    if (e < EE) atomicAdd(&cnt[ei[EE + e]], 1);
}

// Phase B: per-block sums of cnt
__global__ __launch_bounds__(256) void bsum_k(const int* __restrict__ cnt, int* __restrict__ bsum)
{
    __shared__ int s[256];
    int b = blockIdx.x, t = threadIdx.x;
    int i = b * 256 + t;
    s[t] = (i < NN) ? cnt[i] : 0;
    __syncthreads();
    #pragma unroll
    for (int off = 128; off > 0; off >>= 1) {
        if (t < off) s[t] += s[t + off];
        __syncthreads();
    }
    if (t == 0) bsum[b] = s[0];
}

// Phase C: exclusive scan of block sums (single small block)
__global__ __launch_bounds__(256) void scanb_k(const int* __restrict__ bsum, int* __restrict__ boff)
{
    __shared__ int s[256];
    int t = threadIdx.x;
    int v = (t < NBLK) ? bsum[t] : 0;
    s[t] = v;
    __syncthreads();
    #pragma unroll
    for (int off = 1; off < 256; off <<= 1) {
        int add = (t >= off) ? s[t - off] : 0;
        __syncthreads();
        s[t] += add;
        __syncthreads();
    }
    boff[t] = s[t] - v;   // exclusive
}

// Phase D: intra-block exclusive scan + emit rowptr/cursor/dinv
__global__ __launch_bounds__(256) void emit_k(const int* __restrict__ cnt,
                                              const int* __restrict__ boff,
                                              int* __restrict__ rowptr,
                                              int* __restrict__ cursor,
                                              float* __restrict__ dinv)
{
    __shared__ int s[256];
    int b = blockIdx.x, t = threadIdx.x;
    int i = b * 256 + t;
    int v = (i < NN) ? cnt[i] : 0;
    s[t] = v;
    __syncthreads();
    #pragma unroll
    for (int off = 1; off < 256; off <<= 1) {
        int add = (t >= off) ? s[t - off] : 0;
        __syncthreads();
        s[t] += add;
        __syncthreads();
    }
    int run = boff[b] + s[t] - v;   // exclusive prefix
    if (i < NN) {
        rowptr[i] = run;
        cursor[i] = run;
        dinv[i]   = rsqrtf((float)(v + 1));   // deg includes self-loop
        if (i == NN - 1) rowptr[NN] = run + v;
    }
}

// fill packed edge records {src, norm} — ONE scattered 8B write per edge
__global__ void fill_k(const int* __restrict__ ei, const float* __restrict__ dinv,
                       int* __restrict__ cursor, int2* __restrict__ ebuf)
{
    int e = blockIdx.x * 256 + threadIdx.x;
    if (e < EE) {
        int r = ei[e];          // source
        int c = ei[EE + e];     // target
        int p = atomicAdd(&cursor[c], 1);
        ebuf[p] = make_int2(r, __float_as_int(dinv[r] * dinv[c]));
    }
}

// edge-parallel: ebuf2[e] = {batch[src], norm} (coalesced both ways)
__global__ void pb_k(const int2* __restrict__ ebuf, const int* __restrict__ batch,
                     int2* __restrict__ ebuf2)
{
    int e = blockIdx.x * 256 + threadIdx.x;
    if (e < EE) {
        int2 r = ebuf[e];
        ebuf2[e] = make_int2(batch[r.x], r.y);
    }
}

// ---------- GEMM: out[r][c0..c0+64) = in[r][:] @ W[:, c0..c0+64), fp16 output ----------
// 64 cols/thread: input row read only 2x total (gridDim.y=2), W rows via wave-uniform s_loads
__global__ __launch_bounds__(256) void gemm128h_k(const float* __restrict__ in,
                                                  const float* __restrict__ W,
                                                  __half* __restrict__ out,
                                                  int rows)
{
    int r = blockIdx.x * 256 + threadIdx.x;
    if (r >= rows) return;
    int c0 = blockIdx.y * 64;
    const float* rowp = in + (size_t)r * 128;

    float acc[64];
    #pragma unroll
    for (int j = 0; j < 64; j++) acc[j] = 0.f;

    for (int k0 = 0; k0 < 128; k0 += 8) {
        float4 ra = *(const float4*)(rowp + k0);
        float4 rb = *(const float4*)(rowp + k0 + 4);
        float rr[8] = {ra.x, ra.y, ra.z, ra.w, rb.x, rb.y, rb.z, rb.w};
        #pragma unroll
        for (int kk = 0; kk < 8; kk++) {
            const float* wr = W + (size_t)(k0 + kk) * 128 + c0;   // wave-uniform -> s_load
            #pragma unroll
            for (int j = 0; j < 64; j++) acc[j] = fmaf(rr[kk], wr[j], acc[j]);
        }
    }
    // pack 64 f32 -> 64 f16 and store as 8x uint4 (128B contiguous)
    __half2 hb[32];
    #pragma unroll
    for (int j = 0; j < 64; j += 2) hb[j >> 1] = __floats2half2_rn(acc[j], acc[j + 1]);
    uint4* op = (uint4*)(out + (size_t)r * 128 + c0);
    const uint4* hp = (const uint4*)hb;
    #pragma unroll
    for (int q = 0; q < 8; q++) op[q] = hp[q];
}

// ---------- aggregation from fp16 t: out[i] = relu?( sum_e norm*t[src] + dinv[i]^2*t[i] + b ) ----------
// block = node, 64 threads = half2 feature pairs (256B/row gather); edge loop unrolled x8
__global__ __launch_bounds__(64) void aggh_k(const __half* __restrict__ t,
                                             const int* __restrict__ rowptr,
                                             const int2* __restrict__ ebuf,
                                             const float* __restrict__ dinv,
                                             const float* __restrict__ bias,
                                             float* __restrict__ out,
                                             int relu)
{
    int i = blockIdx.x;
    int f = threadIdx.x;
    const __half2* tp = (const __half2*)t;   // row = 64 half2
    float di = dinv[i];
    float sn = di * di;
    float2 v = __half22float2(tp[(size_t)i * 64 + f]);
    float a0 = sn * v.x, a1 = sn * v.y;
    // rowptr values are uniform across the block; hint SGPR-ness for scalar ebuf loads
    int e0 = __builtin_amdgcn_readfirstlane(rowptr[i]);
    int e1 = __builtin_amdgcn_readfirstlane(rowptr[i + 1]);
    int e = e0;
    for (; e + 7 < e1; e += 8) {
        int2 r0 = ebuf[e],     r1 = ebuf[e + 1];
        int2 r2 = ebuf[e + 2], r3 = ebuf[e + 3];
        int2 r4 = ebuf[e + 4], r5 = ebuf[e + 5];
        int2 r6 = ebuf[e + 6], r7 = ebuf[e + 7];
        float2 w0 = __half22float2(tp[(size_t)r0.x * 64 + f]);
        float2 w1 = __half22float2(tp[(size_t)r1.x * 64 + f]);
        float2 w2 = __half22float2(tp[(size_t)r2.x * 64 + f]);
        float2 w3 = __half22float2(tp[(size_t)r3.x * 64 + f]);
        float2 w4 = __half22float2(tp[(size_t)r4.x * 64 + f]);
        float2 w5 = __half22float2(tp[(size_t)r5.x * 64 + f]);
        float2 w6 = __half22float2(tp[(size_t)r6.x * 64 + f]);
        float2 w7 = __half22float2(tp[(size_t)r7.x * 64 + f]);
        float n0 = __int_as_float(r0.y), n1 = __int_as_float(r1.y);
        float n2 = __int_as_float(r2.y), n3 = __int_as_float(r3.y);
        float n4 = __int_as_float(r4.y), n5 = __int_as_float(r5.y);
        float n6 = __int_as_float(r6.y), n7 = __int_as_float(r7.y);
        a0 += n0 * w0.x; a1 += n0 * w0.y;
        a0 += n1 * w1.x; a1 += n1 * w1.y;
        a0 += n2 * w2.x; a1 += n2 * w2.y;
        a0 += n3 * w3.x; a1 += n3 * w3.y;
        a0 += n4 * w4.x; a1 += n4 * w4.y;
        a0 += n5 * w5.x; a1 += n5 * w5.y;
        a0 += n6 * w6.x; a1 += n6 * w6.y;
        a0 += n7 * w7.x; a1 += n7 * w7.y;
    }
    for (; e < e1; e++) {
        int2 r = ebuf[e];
        float nm = __int_as_float(r.y);
        float2 w = __half22float2(tp[(size_t)r.x * 64 + f]);
        a0 += nm * w.x; a1 += nm * w.y;
    }
    float2 b = ((const float2*)bias)[f];
    a0 += b.x; a1 += b.y;
    if (relu) { a0 = fmaxf(a0, 0.f); a1 = fmaxf(a1, 0.f); }
    ((float2*)out)[(size_t)i * 64 + f] = make_float2(a0, a1);
}

// conv3 aggregation: row for edge src is zz[bg] where ebuf2 = {bg, norm}; zz L2-resident
__global__ __launch_bounds__(64) void agg_out_k(const float* __restrict__ zz,
                                                const int* __restrict__ batch,
                                                const int* __restrict__ rowptr,
                                                const int2* __restrict__ ebuf2,
                                                const float* __restrict__ dinv,
                                                const float* __restrict__ bias,
                                                float* __restrict__ out)
{
    int i = blockIdx.x;
    int f = threadIdx.x;
    const float2* zp = (const float2*)zz;
    float di = dinv[i];
    float sn = di * di;
    float2 v = zp[(size_t)batch[i] * 64 + f];
    float a0 = sn * v.x, a1 = sn * v.y;
    int e0 = rowptr[i], e1 = rowptr[i + 1];
    int e = e0;
    for (; e + 3 < e1; e += 4) {
        int2 r0 = ebuf2[e],     r1 = ebuf2[e + 1];
        int2 r2 = ebuf2[e + 2], r3 = ebuf2[e + 3];
        float2 w0 = zp[(size_t)r0.x * 64 + f];
        float2 w1 = zp[(size_t)r1.x * 64 + f];
        float2 w2 = zp[(size_t)r2.x * 64 + f];
        float2 w3 = zp[(size_t)r3.x * 64 + f];
        float n0 = __int_as_float(r0.y), n1 = __int_as_float(r1.y);
        float n2 = __int_as_float(r2.y), n3 = __int_as_float(r3.y);
        a0 += n0 * w0.x; a1 += n0 * w0.y;
        a0 += n1 * w1.x; a1 += n1 * w1.y;
        a0 += n2 * w2.x; a1 += n2 * w2.y;
        a0 += n3 * w3.x; a1 += n3 * w3.y;
    }
    for (; e < e1; e++) {
        int2 r = ebuf2[e];
        float nm = __int_as_float(r.y);
        float2 w = zp[(size_t)r.x * 64 + f];
        a0 += nm * w.x; a1 += nm * w.y;
    }
    float2 b = ((const float2*)bias)[f];
    a0 += b.x; a1 += b.y;
    ((float2*)out)[(size_t)i * 64 + f] = make_float2(a0, a1);
}

// ---------- pooling (parallel): pooled[g][f] += partial sums over chunk c of graph g ----------
__global__ __launch_bounds__(128) void pool2_k(const float* __restrict__ h2,
                                               const int* __restrict__ batch,
                                               float* __restrict__ pooled)
{
    int g = blockIdx.x;
    int c = blockIdx.y;
    int f = threadIdx.x;
    int bs = lowerb(batch, NN, g);
    int be = lowerb(batch, NN, g + 1);
    int len = be - bs;
    int cs = bs + (int)(((long long)len * c) / PCH);
    int ce = bs + (int)(((long long)len * (c + 1)) / PCH);
    float a = 0.f;
    for (int i = cs; i < ce; i++) a += h2[(size_t)i * 128 + f];
    if (ce > cs) atomicAdd(&pooled[(size_t)g * 128 + f], a);
}

// ---------- fc: latent = relu(pooled @ fcW + fcb); writes latent to d_out too ----------
__global__ __launch_bounds__(64) void fc_k(const float* __restrict__ pooled,
                                           const float* __restrict__ fcW,    // [128][64]
                                           const float* __restrict__ fcb,
                                           float* __restrict__ latentf,
                                           float* __restrict__ lat_out)
{
    int g = blockIdx.x, l = threadIdx.x;
    const float* p = pooled + (size_t)g * 128;
    float a = fcb[l];
    #pragma unroll 8
    for (int k = 0; k < 128; k++) a = fmaf(p[k], fcW[(size_t)k * 64 + l], a);
    a = fmaxf(a, 0.f);
    latentf[(size_t)g * 64 + l] = a;
    lat_out[(size_t)g * 64 + l] = a;
}

// ---------- decoder + W3 transform: zz = relu(latent@decW + decb) @ W3 ----------
__global__ __launch_bounds__(128) void dec_k(const float* __restrict__ latentf,
                                             const float* __restrict__ decW,  // [64][128]
                                             const float* __restrict__ decb,
                                             const float* __restrict__ W3,    // [128][128]
                                             float* __restrict__ zz)
{
    __shared__ float zs[128];
    int g = blockIdx.x, c = threadIdx.x;
    const float* lat = latentf + (size_t)g * 64;
    {
        float a = decb[c];
        #pragma unroll 8
        for (int k = 0; k < 64; k++) a = fmaf(lat[k], decW[(size_t)k * 128 + c], a);
        zs[c] = fmaxf(a, 0.f);
    }
    __syncthreads();
    float o = 0.f;
    #pragma unroll 8
    for (int k = 0; k < 128; k++) o = fmaf(zs[k], W3[(size_t)k * 128 + c], o);
    zz[(size_t)g * 128 + c] = o;
}

extern "C" void kernel_launch(void* const* d_in, const int* in_sizes, int n_in,
                              void* d_out, int out_size, void* d_ws, size_t ws_size,
                              hipStream_t stream)
{
    const float* x     = (const float*)d_in[0];
    const int*   ei    = (const int*)d_in[1];
    const int*   batch = (const int*)d_in[2];
    const float* W1  = (const float*)d_in[3];
    const float* b1  = (const float*)d_in[4];
    const float* W2  = (const float*)d_in[5];
    const float* b2  = (const float*)d_in[6];
    const float* fcW = (const float*)d_in[7];
    const float* fcb = (const float*)d_in[8];
    const float* decW= (const float*)d_in[9];
    const float* decb= (const float*)d_in[10];
    const float* W3  = (const float*)d_in[11];
    const float* b3  = (const float*)d_in[12];

    char* ws = (char*)d_ws;
    size_t off = 0;
    auto alloc = [&](size_t bytes) -> char* {
        char* p = ws + off;
        off = (off + bytes + 255) & ~(size_t)255;
        return p;
    };
    float* dinv     = (float*)alloc((size_t)NN * 4);
    int*   cnt      = (int*)alloc((size_t)NN * 4);
    int*   rowptr   = (int*)alloc((size_t)(NN + 1) * 4);
    int*   cursor   = (int*)alloc((size_t)NN * 4);
    int*   bsum     = (int*)alloc((size_t)NBLK * 4);
    int*   boff     = (int*)alloc(256 * 4);
    int2*  ebuf     = (int2*)alloc((size_t)EE * 8);          // packed {src, norm}
    float* pooled   = (float*)alloc((size_t)GG * 128 * 4);
    float* latentf  = (float*)alloc((size_t)GG * 64 * 4);
    float* zz       = (float*)alloc((size_t)GG * 128 * 4);
    __half* A       = (__half*)alloc((size_t)NN * 128 * 2);  // transformed features t (fp16)
    float* B        = (float*)alloc((size_t)NN * 128 * 4);   // hidden activations h (f32)
    // ebuf2 aliases A (6.4MB <= 12.8MB): built only AFTER the 2nd aggh has consumed A
    int2*  ebuf2    = (int2*)A;

    float* recon_out = (float*)d_out;
    float* lat_out   = (float*)d_out + (size_t)NN * 128;

    hipMemsetAsync(cnt, 0, (size_t)NN * 4, stream);
    hipMemsetAsync(pooled, 0, (size_t)GG * 128 * 4, stream);
    count_k<<<(EE + 255) / 256, 256, 0, stream>>>(ei, cnt);
    bsum_k<<<NBLK, 256, 0, stream>>>(cnt, bsum);
    scanb_k<<<1, 256, 0, stream>>>(bsum, boff);
    emit_k<<<NBLK, 256, 0, stream>>>(cnt, boff, rowptr, cursor, dinv);
    fill_k<<<(EE + 255) / 256, 256, 0, stream>>>(ei, dinv, cursor, ebuf);

    dim3 ggrid((NN + 255) / 256, 2);
    // conv1: t1 = x @ W1 -> A (fp16) ; h1 = relu(agg(A) + b1) -> B
    gemm128h_k<<<ggrid, 256, 0, stream>>>(x, W1, A, NN);
    aggh_k<<<NN, 64, 0, stream>>>(A, rowptr, ebuf, dinv, b1, B, 1);
    // conv2: t2 = h1 @ W2 -> A (fp16) ; h2 = relu(agg(A) + b2) -> B
    gemm128h_k<<<ggrid, 256, 0, stream>>>(B, W2, A, NN);
    aggh_k<<<NN, 64, 0, stream>>>(A, rowptr, ebuf, dinv, b2, B, 1);
    // A is now free -> build ebuf2 in its space
    pb_k<<<(EE + 255) / 256, 256, 0, stream>>>(ebuf, batch, ebuf2);
    // pool + fc (latent out) + decoder(+W3 transform)
    pool2_k<<<dim3(GG, PCH), 128, 0, stream>>>(B, batch, pooled);
    fc_k<<<GG, 64, 0, stream>>>(pooled, fcW, fcb, latentf, lat_out);
    dec_k<<<GG, 128, 0, stream>>>(latentf, decW, decb, W3, zz);
    // conv3 -> recon
    agg_out_k<<<NN, 64, 0, stream>>>(zz, batch, rowptr, ebuf2, dinv,
                                     b3, recon_out);
}

// Round 2
// 381.414 us; speedup vs baseline: 1.1231x; 1.0340x over previous
//
#include <hip/hip_runtime.h>
#include <hip/hip_fp16.h>

// Problem constants
static constexpr int NN   = 50000;
static constexpr int EE   = 800000;
static constexpr int GG   = 256;
static constexpr int NBLK = (NN + 255) / 256;   // 196
static constexpr int PCH  = 16;                 // pooling chunks per graph

// ---------- helpers ----------
__device__ __forceinline__ int lowerb(const int* __restrict__ b, int n, int v) {
    int lo = 0, hi = n;
    while (lo < hi) { int m = (lo + hi) >> 1; if (b[m] < v) lo = m + 1; else hi = m; }
    return lo;
}

// ---------- CSR build (by target node = col) ----------
__global__ void count_k(const int* __restrict__ ei, int* __restrict__ cnt)
{
    int e = blockIdx.x * 256 + threadIdx.x;
    if (e < EE) atomicAdd(&cnt[ei[EE + e]], 1);
}

// Phase B: per-block sums of cnt
__global__ __launch_bounds__(256) void bsum_k(const int* __restrict__ cnt, int* __restrict__ bsum)
{
    __shared__ int s[256];
    int b = blockIdx.x, t = threadIdx.x;
    int i = b * 256 + t;
    s[t] = (i < NN) ? cnt[i] : 0;
    __syncthreads();
    #pragma unroll
    for (int off = 128; off > 0; off >>= 1) {
        if (t < off) s[t] += s[t + off];
        __syncthreads();
    }
    if (t == 0) bsum[b] = s[0];
}

// Phase C: exclusive scan of block sums (single small block)
__global__ __launch_bounds__(256) void scanb_k(const int* __restrict__ bsum, int* __restrict__ boff)
{
    __shared__ int s[256];
    int t = threadIdx.x;
    int v = (t < NBLK) ? bsum[t] : 0;
    s[t] = v;
    __syncthreads();
    #pragma unroll
    for (int off = 1; off < 256; off <<= 1) {
        int add = (t >= off) ? s[t - off] : 0;
        __syncthreads();
        s[t] += add;
        __syncthreads();
    }
    boff[t] = s[t] - v;   // exclusive
}

// Phase D: intra-block exclusive scan + emit rowptr/cursor/dinv
__global__ __launch_bounds__(256) void emit_k(const int* __restrict__ cnt,
                                              const int* __restrict__ boff,
                                              int* __restrict__ rowptr,
                                              int* __restrict__ cursor,
                                              float* __restrict__ dinv)
{
    __shared__ int s[256];
    int b = blockIdx.x, t = threadIdx.x;
    int i = b * 256 + t;
    int v = (i < NN) ? cnt[i] : 0;
    s[t] = v;
    __syncthreads();
    #pragma unroll
    for (int off = 1; off < 256; off <<= 1) {
        int add = (t >= off) ? s[t - off] : 0;
        __syncthreads();
        s[t] += add;
        __syncthreads();
    }
    int run = boff[b] + s[t] - v;   // exclusive prefix
    if (i < NN) {
        rowptr[i] = run;
        cursor[i] = run;
        dinv[i]   = rsqrtf((float)(v + 1));   // deg includes self-loop
        if (i == NN - 1) rowptr[NN] = run + v;
    }
}

// fill packed edge records {src, norm} — ONE scattered 8B write per edge
__global__ void fill_k(const int* __restrict__ ei, const float* __restrict__ dinv,
                       int* __restrict__ cursor, int2* __restrict__ ebuf)
{
    int e = blockIdx.x * 256 + threadIdx.x;
    if (e < EE) {
        int r = ei[e];          // source
        int c = ei[EE + e];     // target
        int p = atomicAdd(&cursor[c], 1);
        ebuf[p] = make_int2(r, __float_as_int(dinv[r] * dinv[c]));
    }
}

// edge-parallel: ebuf2[e] = {batch[src], norm} (coalesced both ways)
__global__ void pb_k(const int2* __restrict__ ebuf, const int* __restrict__ batch,
                     int2* __restrict__ ebuf2)
{
    int e = blockIdx.x * 256 + threadIdx.x;
    if (e < EE) {
        int2 r = ebuf[e];
        ebuf2[e] = make_int2(batch[r.x], r.y);
    }
}

// ---------- GEMM: out[r][c0..c0+16) = in[r][:] @ W[:, c0..c0+16), fp16 output ----------
// 16 cols/thread, gridDim.y=8 -> 6272 waves (latency hidden); input re-reads served by L2/L3
__global__ __launch_bounds__(256) void gemm128h_k(const float* __restrict__ in,
                                                  const float* __restrict__ W,
                                                  __half* __restrict__ out,
                                                  int rows)
{
    int r = blockIdx.x * 256 + threadIdx.x;
    if (r >= rows) return;
    int c0 = blockIdx.y * 16;
    const float* rowp = in + (size_t)r * 128;

    float acc[16];
    #pragma unroll
    for (int j = 0; j < 16; j++) acc[j] = 0.f;

    #pragma unroll 4
    for (int k0 = 0; k0 < 128; k0 += 8) {
        float4 ra = *(const float4*)(rowp + k0);
        float4 rb = *(const float4*)(rowp + k0 + 4);
        float rr[8] = {ra.x, ra.y, ra.z, ra.w, rb.x, rb.y, rb.z, rb.w};
        #pragma unroll
        for (int kk = 0; kk < 8; kk++) {
            const float* wr = W + (size_t)(k0 + kk) * 128 + c0;   // wave-uniform -> s_load
            #pragma unroll
            for (int j = 0; j < 16; j++) acc[j] = fmaf(rr[kk], wr[j], acc[j]);
        }
    }
    // pack 16 f32 -> 16 f16, one 32B store
    __half2 hb[8];
    #pragma unroll
    for (int j = 0; j < 16; j += 2) hb[j >> 1] = __floats2half2_rn(acc[j], acc[j + 1]);
    uint4* op = (uint4*)(out + (size_t)r * 128 + c0);
    const uint4* hp = (const uint4*)hb;
    op[0] = hp[0];
    op[1] = hp[1];
}

// ---------- aggregation from fp16 t: out[i] = relu?( sum_e norm*t[src] + dinv[i]^2*t[i] + b ) ----------
// block = node, 64 threads = half2 feature pairs (256B/row gather); edge loop unrolled x8
__global__ __launch_bounds__(64) void aggh_k(const __half* __restrict__ t,
                                             const int* __restrict__ rowptr,
                                             const int2* __restrict__ ebuf,
                                             const float* __restrict__ dinv,
                                             const float* __restrict__ bias,
                                             float* __restrict__ out,
                                             int relu)
{
    int i = blockIdx.x;
    int f = threadIdx.x;
    const __half2* tp = (const __half2*)t;   // row = 64 half2
    float di = dinv[i];
    float sn = di * di;
    float2 v = __half22float2(tp[(size_t)i * 64 + f]);
    float a0 = sn * v.x, a1 = sn * v.y;
    // rowptr values are uniform across the block; hint SGPR-ness for scalar ebuf loads
    int e0 = __builtin_amdgcn_readfirstlane(rowptr[i]);
    int e1 = __builtin_amdgcn_readfirstlane(rowptr[i + 1]);
    int e = e0;
    for (; e + 7 < e1; e += 8) {
        int2 r0 = ebuf[e],     r1 = ebuf[e + 1];
        int2 r2 = ebuf[e + 2], r3 = ebuf[e + 3];
        int2 r4 = ebuf[e + 4], r5 = ebuf[e + 5];
        int2 r6 = ebuf[e + 6], r7 = ebuf[e + 7];
        float2 w0 = __half22float2(tp[(size_t)r0.x * 64 + f]);
        float2 w1 = __half22float2(tp[(size_t)r1.x * 64 + f]);
        float2 w2 = __half22float2(tp[(size_t)r2.x * 64 + f]);
        float2 w3 = __half22float2(tp[(size_t)r3.x * 64 + f]);
        float2 w4 = __half22float2(tp[(size_t)r4.x * 64 + f]);
        float2 w5 = __half22float2(tp[(size_t)r5.x * 64 + f]);
        float2 w6 = __half22float2(tp[(size_t)r6.x * 64 + f]);
        float2 w7 = __half22float2(tp[(size_t)r7.x * 64 + f]);
        float n0 = __int_as_float(r0.y), n1 = __int_as_float(r1.y);
        float n2 = __int_as_float(r2.y), n3 = __int_as_float(r3.y);
        float n4 = __int_as_float(r4.y), n5 = __int_as_float(r5.y);
        float n6 = __int_as_float(r6.y), n7 = __int_as_float(r7.y);
        a0 += n0 * w0.x; a1 += n0 * w0.y;
        a0 += n1 * w1.x; a1 += n1 * w1.y;
        a0 += n2 * w2.x; a1 += n2 * w2.y;
        a0 += n3 * w3.x; a1 += n3 * w3.y;
        a0 += n4 * w4.x; a1 += n4 * w4.y;
        a0 += n5 * w5.x; a1 += n5 * w5.y;
        a0 += n6 * w6.x; a1 += n6 * w6.y;
        a0 += n7 * w7.x; a1 += n7 * w7.y;
    }
    for (; e < e1; e++) {
        int2 r = ebuf[e];
        float nm = __int_as_float(r.y);
        float2 w = __half22float2(tp[(size_t)r.x * 64 + f]);
        a0 += nm * w.x; a1 += nm * w.y;
    }
    float2 b = ((const float2*)bias)[f];
    a0 += b.x; a1 += b.y;
    if (relu) { a0 = fmaxf(a0, 0.f); a1 = fmaxf(a1, 0.f); }
    ((float2*)out)[(size_t)i * 64 + f] = make_float2(a0, a1);
}

// conv3 aggregation: row for edge src is zz[bg] where ebuf2 = {bg, norm}; zz L2-resident
__global__ __launch_bounds__(64) void agg_out_k(const float* __restrict__ zz,
                                                const int* __restrict__ batch,
                                                const int* __restrict__ rowptr,
                                                const int2* __restrict__ ebuf2,
                                                const float* __restrict__ dinv,
                                                const float* __restrict__ bias,
                                                float* __restrict__ out)
{
    int i = blockIdx.x;
    int f = threadIdx.x;
    const float2* zp = (const float2*)zz;
    float di = dinv[i];
    float sn = di * di;
    float2 v = zp[(size_t)batch[i] * 64 + f];
    float a0 = sn * v.x, a1 = sn * v.y;
    int e0 = rowptr[i], e1 = rowptr[i + 1];
    int e = e0;
    for (; e + 3 < e1; e += 4) {
        int2 r0 = ebuf2[e],     r1 = ebuf2[e + 1];
        int2 r2 = ebuf2[e + 2], r3 = ebuf2[e + 3];
        float2 w0 = zp[(size_t)r0.x * 64 + f];
        float2 w1 = zp[(size_t)r1.x * 64 + f];
        float2 w2 = zp[(size_t)r2.x * 64 + f];
        float2 w3 = zp[(size_t)r3.x * 64 + f];
        float n0 = __int_as_float(r0.y), n1 = __int_as_float(r1.y);
        float n2 = __int_as_float(r2.y), n3 = __int_as_float(r3.y);
        a0 += n0 * w0.x; a1 += n0 * w0.y;
        a0 += n1 * w1.x; a1 += n1 * w1.y;
        a0 += n2 * w2.x; a1 += n2 * w2.y;
        a0 += n3 * w3.x; a1 += n3 * w3.y;
    }
    for (; e < e1; e++) {
        int2 r = ebuf2[e];
        float nm = __int_as_float(r.y);
        float2 w = zp[(size_t)r.x * 64 + f];
        a0 += nm * w.x; a1 += nm * w.y;
    }
    float2 b = ((const float2*)bias)[f];
    a0 += b.x; a1 += b.y;
    ((float2*)out)[(size_t)i * 64 + f] = make_float2(a0, a1);
}

// ---------- pooling (parallel): pooled[g][f] += partial sums over chunk c of graph g ----------
__global__ __launch_bounds__(128) void pool2_k(const float* __restrict__ h2,
                                               const int* __restrict__ batch,
                                               float* __restrict__ pooled)
{
    int g = blockIdx.x;
    int c = blockIdx.y;
    int f = threadIdx.x;
    int bs = lowerb(batch, NN, g);
    int be = lowerb(batch, NN, g + 1);
    int len = be - bs;
    int cs = bs + (int)(((long long)len * c) / PCH);
    int ce = bs + (int)(((long long)len * (c + 1)) / PCH);
    float a = 0.f;
    for (int i = cs; i < ce; i++) a += h2[(size_t)i * 128 + f];
    if (ce > cs) atomicAdd(&pooled[(size_t)g * 128 + f], a);
}

// ---------- fc: latent = relu(pooled @ fcW + fcb); writes latent to d_out too ----------
__global__ __launch_bounds__(64) void fc_k(const float* __restrict__ pooled,
                                           const float* __restrict__ fcW,    // [128][64]
                                           const float* __restrict__ fcb,
                                           float* __restrict__ latentf,
                                           float* __restrict__ lat_out)
{
    int g = blockIdx.x, l = threadIdx.x;
    const float* p = pooled + (size_t)g * 128;
    float a = fcb[l];
    #pragma unroll 8
    for (int k = 0; k < 128; k++) a = fmaf(p[k], fcW[(size_t)k * 64 + l], a);
    a = fmaxf(a, 0.f);
    latentf[(size_t)g * 64 + l] = a;
    lat_out[(size_t)g * 64 + l] = a;
}

// ---------- decoder + W3 transform: zz = relu(latent@decW + decb) @ W3 ----------
__global__ __launch_bounds__(128) void dec_k(const float* __restrict__ latentf,
                                             const float* __restrict__ decW,  // [64][128]
                                             const float* __restrict__ decb,
                                             const float* __restrict__ W3,    // [128][128]
                                             float* __restrict__ zz)
{
    __shared__ float zs[128];
    int g = blockIdx.x, c = threadIdx.x;
    const float* lat = latentf + (size_t)g * 64;
    {
        float a = decb[c];
        #pragma unroll 8
        for (int k = 0; k < 64; k++) a = fmaf(lat[k], decW[(size_t)k * 128 + c], a);
        zs[c] = fmaxf(a, 0.f);
    }
    __syncthreads();
    float o = 0.f;
    #pragma unroll 8
    for (int k = 0; k < 128; k++) o = fmaf(zs[k], W3[(size_t)k * 128 + c], o);
    zz[(size_t)g * 128 + c] = o;
}

extern "C" void kernel_launch(void* const* d_in, const int* in_sizes, int n_in,
                              void* d_out, int out_size, void* d_ws, size_t ws_size,
                              hipStream_t stream)
{
    const float* x     = (const float*)d_in[0];
    const int*   ei    = (const int*)d_in[1];
    const int*   batch = (const int*)d_in[2];
    const float* W1  = (const float*)d_in[3];
    const float* b1  = (const float*)d_in[4];
    const float* W2  = (const float*)d_in[5];
    const float* b2  = (const float*)d_in[6];
    const float* fcW = (const float*)d_in[7];
    const float* fcb = (const float*)d_in[8];
    const float* decW= (const float*)d_in[9];
    const float* decb= (const float*)d_in[10];
    const float* W3  = (const float*)d_in[11];
    const float* b3  = (const float*)d_in[12];

    char* ws = (char*)d_ws;
    size_t off = 0;
    auto alloc = [&](size_t bytes) -> char* {
        char* p = ws + off;
        off = (off + bytes + 255) & ~(size_t)255;
        return p;
    };
    float* dinv     = (float*)alloc((size_t)NN * 4);
    int*   cnt      = (int*)alloc((size_t)NN * 4);
    int*   rowptr   = (int*)alloc((size_t)(NN + 1) * 4);
    int*   cursor   = (int*)alloc((size_t)NN * 4);
    int*   bsum     = (int*)alloc((size_t)NBLK * 4);
    int*   boff     = (int*)alloc(256 * 4);
    int2*  ebuf     = (int2*)alloc((size_t)EE * 8);          // packed {src, norm}
    float* pooled   = (float*)alloc((size_t)GG * 128 * 4);
    float* latentf  = (float*)alloc((size_t)GG * 64 * 4);
    float* zz       = (float*)alloc((size_t)GG * 128 * 4);
    __half* A       = (__half*)alloc((size_t)NN * 128 * 2);  // transformed features t (fp16)
    float* B        = (float*)alloc((size_t)NN * 128 * 4);   // hidden activations h (f32)
    // ebuf2 aliases A (6.4MB <= 12.8MB): built only AFTER the 2nd aggh has consumed A
    int2*  ebuf2    = (int2*)A;

    float* recon_out = (float*)d_out;
    float* lat_out   = (float*)d_out + (size_t)NN * 128;

    hipMemsetAsync(cnt, 0, (size_t)NN * 4, stream);
    hipMemsetAsync(pooled, 0, (size_t)GG * 128 * 4, stream);
    count_k<<<(EE + 255) / 256, 256, 0, stream>>>(ei, cnt);
    bsum_k<<<NBLK, 256, 0, stream>>>(cnt, bsum);
    scanb_k<<<1, 256, 0, stream>>>(bsum, boff);
    emit_k<<<NBLK, 256, 0, stream>>>(cnt, boff, rowptr, cursor, dinv);
    fill_k<<<(EE + 255) / 256, 256, 0, stream>>>(ei, dinv, cursor, ebuf);

    dim3 ggrid((NN + 255) / 256, 8);
    // conv1: t1 = x @ W1 -> A (fp16) ; h1 = relu(agg(A) + b1) -> B
    gemm128h_k<<<ggrid, 256, 0, stream>>>(x, W1, A, NN);
    aggh_k<<<NN, 64, 0, stream>>>(A, rowptr, ebuf, dinv, b1, B, 1);
    // conv2: t2 = h1 @ W2 -> A (fp16) ; h2 = relu(agg(A) + b2) -> B
    gemm128h_k<<<ggrid, 256, 0, stream>>>(B, W2, A, NN);
    aggh_k<<<NN, 64, 0, stream>>>(A, rowptr, ebuf, dinv, b2, B, 1);
    // A is now free -> build ebuf2 in its space
    pb_k<<<(EE + 255) / 256, 256, 0, stream>>>(ebuf, batch, ebuf2);
    // pool + fc (latent out) + decoder(+W3 transform)
    pool2_k<<<dim3(GG, PCH), 128, 0, stream>>>(B, batch, pooled);
    fc_k<<<GG, 64, 0, stream>>>(pooled, fcW, fcb, latentf, lat_out);
    dec_k<<<GG, 128, 0, stream>>>(latentf, decW, decb, W3, zz);
    // conv3 -> recon
    agg_out_k<<<NN, 64, 0, stream>>>(zz, batch, rowptr, ebuf2, dinv,
                                     b3, recon_out);
}

// Round 3
// 365.861 us; speedup vs baseline: 1.1708x; 1.0425x over previous
//
#include <hip/hip_runtime.h>
#include <hip/hip_fp16.h>

// Problem constants
static constexpr int NN   = 50000;
static constexpr int EE   = 800000;
static constexpr int GG   = 256;
static constexpr int NBLK = (NN + 255) / 256;   // 196
static constexpr int PCH  = 16;                 // pooling chunks per graph
static constexpr int NB   = (NN + 255) / 256;   // 196 target-range buckets (bucket = dst>>8)
static constexpr int CH   = 4096;               // edges per binA block
static constexpr int ABLK = (EE + CH - 1) / CH; // 196

// ---------- helpers ----------
__device__ __forceinline__ int lowerb(const int* __restrict__ b, int n, int v) {
    int lo = 0, hi = n;
    while (lo < hi) { int m = (lo + hi) >> 1; if (b[m] < v) lo = m + 1; else hi = m; }
    return lo;
}

// ---------- CSR build (by target node = col) ----------
__global__ void count_k(const int* __restrict__ ei, int* __restrict__ cnt)
{
    int e = blockIdx.x * 256 + threadIdx.x;
    if (e < EE) atomicAdd(&cnt[ei[EE + e]], 1);
}

// Phase B: per-block sums of cnt
__global__ __launch_bounds__(256) void bsum_k(const int* __restrict__ cnt, int* __restrict__ bsum)
{
    __shared__ int s[256];
    int b = blockIdx.x, t = threadIdx.x;
    int i = b * 256 + t;
    s[t] = (i < NN) ? cnt[i] : 0;
    __syncthreads();
    #pragma unroll
    for (int off = 128; off > 0; off >>= 1) {
        if (t < off) s[t] += s[t + off];
        __syncthreads();
    }
    if (t == 0) bsum[b] = s[0];
}

// Phase C: exclusive scan of block sums (single small block)
__global__ __launch_bounds__(256) void scanb_k(const int* __restrict__ bsum, int* __restrict__ boff)
{
    __shared__ int s[256];
    int t = threadIdx.x;
    int v = (t < NBLK) ? bsum[t] : 0;
    s[t] = v;
    __syncthreads();
    #pragma unroll
    for (int off = 1; off < 256; off <<= 1) {
        int add = (t >= off) ? s[t - off] : 0;
        __syncthreads();
        s[t] += add;
        __syncthreads();
    }
    boff[t] = s[t] - v;   // exclusive
}

// Phase D: intra-block exclusive scan + emit rowptr/dinv + bucket cursors
__global__ __launch_bounds__(256) void emit_k(const int* __restrict__ cnt,
                                              const int* __restrict__ boff,
                                              int* __restrict__ rowptr,
                                              int* __restrict__ bcur,
                                              float* __restrict__ dinv)
{
    __shared__ int s[256];
    int b = blockIdx.x, t = threadIdx.x;
    int i = b * 256 + t;
    int v = (i < NN) ? cnt[i] : 0;
    s[t] = v;
    __syncthreads();
    #pragma unroll
    for (int off = 1; off < 256; off <<= 1) {
        int add = (t >= off) ? s[t - off] : 0;
        __syncthreads();
        s[t] += add;
        __syncthreads();
    }
    int run = boff[b] + s[t] - v;   // exclusive prefix = rowptr[i]
    if (i < NN) {
        rowptr[i] = run;
        if ((i & 255) == 0) bcur[i >> 8] = run;   // bucket write cursor = region start
        dinv[i] = rsqrtf((float)(v + 1));         // deg includes self-loop
        if (i == NN - 1) rowptr[NN] = run + v;
    }
}

// ---------- Pass A: partition edges into target-range buckets, coalesced flush ----------
// Each block: histogram 4096 edges by dst>>8, reserve exact global ranges (bcur starts at
// rowptr[b<<8], so bucket regions are exactly final CSR regions), group in LDS, flush runs.
__global__ __launch_bounds__(256) void binA_k(const int* __restrict__ ei,
                                              int* __restrict__ bcur,
                                              int2* __restrict__ eraw)
{
    __shared__ int2  stage[CH];
    __shared__ short sbid[CH];
    __shared__ int   hist[NB], loff[NB], gbase[NB], lcur[NB];

    int tid = threadIdx.x;
    int e0 = blockIdx.x * CH;
    int n = EE - e0; if (n > CH) n = CH;

    for (int b = tid; b < NB; b += 256) hist[b] = 0;
    __syncthreads();

    int2 r[CH / 256];
    #pragma unroll
    for (int k = 0; k < CH / 256; k++) {
        int s = k * 256 + tid;
        if (s < n) {
            int src = ei[e0 + s];
            int dst = ei[EE + e0 + s];
            r[k] = make_int2(src, dst);
            atomicAdd(&hist[dst >> 8], 1);
        }
    }
    __syncthreads();
    if (tid == 0) {
        int run = 0;
        for (int b = 0; b < NB; b++) { int h = hist[b]; loff[b] = run; lcur[b] = run; run += h; }
    }
    __syncthreads();
    for (int b = tid; b < NB; b += 256)
        gbase[b] = atomicAdd(&bcur[b], hist[b]);
    __syncthreads();
    #pragma unroll
    for (int k = 0; k < CH / 256; k++) {
        int s = k * 256 + tid;
        if (s < n) {
            int b = r[k].y >> 8;
            int slot = atomicAdd(&lcur[b], 1);
            stage[slot] = r[k];
            sbid[slot]  = (short)b;
        }
    }
    __syncthreads();
    for (int s = tid; s < n; s += 256) {
        int b = sbid[s];
        eraw[gbase[b] + (s - loff[b])] = stage[s];   // coalesced per-bucket runs
    }
}

// ---------- Pass B: within each bucket, place edges at exact CSR slots ----------
// One block per bucket. Per-target cursors in LDS; scattered writes confined to the
// bucket's ~32KB window, all from one CU -> L2 merges lines -> ~1x write volume.
__global__ __launch_bounds__(256) void binB_k(const int2* __restrict__ eraw,
                                              const int* __restrict__ rowptr,
                                              const float* __restrict__ dinv,
                                              int2* __restrict__ ebuf)
{
    __shared__ int   cur[256];
    __shared__ float sdv[256];
    int b = blockIdx.x, tid = threadIdx.x;
    int t0 = b << 8;
    int t1 = t0 + 256; if (t1 > NN) t1 = NN;
    if (t0 + tid < t1) {
        cur[tid] = rowptr[t0 + tid];
        sdv[tid] = dinv[t0 + tid];
    }
    __syncthreads();
    int base = rowptr[t0];
    int end  = rowptr[t1];
    for (int s = base + tid; s < end; s += 256) {
        int2 rec = eraw[s];            // coalesced read
        int src = rec.x, dst = rec.y;
        int lt = dst & 255;
        float nm = dinv[src] * sdv[lt];
        int p = atomicAdd(&cur[lt], 1);
        ebuf[p] = make_int2(src, __float_as_int(nm));
    }
}

// edge-parallel: ebuf2[e] = {batch[src], norm} (coalesced both ways)
__global__ void pb_k(const int2* __restrict__ ebuf, const int* __restrict__ batch,
                     int2* __restrict__ ebuf2)
{
    int e = blockIdx.x * 256 + threadIdx.x;
    if (e < EE) {
        int2 r = ebuf[e];
        ebuf2[e] = make_int2(batch[r.x], r.y);
    }
}

// ---------- GEMM: out[r][c0..c0+16) = in[r][:] @ W[:, c0..c0+16), fp16 output ----------
// 16 cols/thread, gridDim.y=8 -> 6272 waves (latency hidden); input re-reads served by L2/L3
__global__ __launch_bounds__(256) void gemm128h_k(const float* __restrict__ in,
                                                  const float* __restrict__ W,
                                                  __half* __restrict__ out,
                                                  int rows)
{
    int r = blockIdx.x * 256 + threadIdx.x;
    if (r >= rows) return;
    int c0 = blockIdx.y * 16;
    const float* rowp = in + (size_t)r * 128;

    float acc[16];
    #pragma unroll
    for (int j = 0; j < 16; j++) acc[j] = 0.f;

    #pragma unroll 4
    for (int k0 = 0; k0 < 128; k0 += 8) {
        float4 ra = *(const float4*)(rowp + k0);
        float4 rb = *(const float4*)(rowp + k0 + 4);
        float rr[8] = {ra.x, ra.y, ra.z, ra.w, rb.x, rb.y, rb.z, rb.w};
        #pragma unroll
        for (int kk = 0; kk < 8; kk++) {
            const float* wr = W + (size_t)(k0 + kk) * 128 + c0;   // wave-uniform -> s_load
            #pragma unroll
            for (int j = 0; j < 16; j++) acc[j] = fmaf(rr[kk], wr[j], acc[j]);
        }
    }
    // pack 16 f32 -> 16 f16, one 32B store
    __half2 hb[8];
    #pragma unroll
    for (int j = 0; j < 16; j += 2) hb[j >> 1] = __floats2half2_rn(acc[j], acc[j + 1]);
    uint4* op = (uint4*)(out + (size_t)r * 128 + c0);
    const uint4* hp = (const uint4*)hb;
    op[0] = hp[0];
    op[1] = hp[1];
}

// ---------- aggregation from fp16 t: out[i] = relu?( sum_e norm*t[src] + dinv[i]^2*t[i] + b ) ----------
// block = node, 64 threads = half2 feature pairs (256B/row gather); edge loop unrolled x8
__global__ __launch_bounds__(64) void aggh_k(const __half* __restrict__ t,
                                             const int* __restrict__ rowptr,
                                             const int2* __restrict__ ebuf,
                                             const float* __restrict__ dinv,
                                             const float* __restrict__ bias,
                                             float* __restrict__ out,
                                             int relu)
{
    int i = blockIdx.x;
    int f = threadIdx.x;
    const __half2* tp = (const __half2*)t;   // row = 64 half2
    float di = dinv[i];
    float sn = di * di;
    float2 v = __half22float2(tp[(size_t)i * 64 + f]);
    float a0 = sn * v.x, a1 = sn * v.y;
    // rowptr values are uniform across the block; hint SGPR-ness for scalar ebuf loads
    int e0 = __builtin_amdgcn_readfirstlane(rowptr[i]);
    int e1 = __builtin_amdgcn_readfirstlane(rowptr[i + 1]);
    int e = e0;
    for (; e + 7 < e1; e += 8) {
        int2 r0 = ebuf[e],     r1 = ebuf[e + 1];
        int2 r2 = ebuf[e + 2], r3 = ebuf[e + 3];
        int2 r4 = ebuf[e + 4], r5 = ebuf[e + 5];
        int2 r6 = ebuf[e + 6], r7 = ebuf[e + 7];
        float2 w0 = __half22float2(tp[(size_t)r0.x * 64 + f]);
        float2 w1 = __half22float2(tp[(size_t)r1.x * 64 + f]);
        float2 w2 = __half22float2(tp[(size_t)r2.x * 64 + f]);
        float2 w3 = __half22float2(tp[(size_t)r3.x * 64 + f]);
        float2 w4 = __half22float2(tp[(size_t)r4.x * 64 + f]);
        float2 w5 = __half22float2(tp[(size_t)r5.x * 64 + f]);
        float2 w6 = __half22float2(tp[(size_t)r6.x * 64 + f]);
        float2 w7 = __half22float2(tp[(size_t)r7.x * 64 + f]);
        float n0 = __int_as_float(r0.y), n1 = __int_as_float(r1.y);
        float n2 = __int_as_float(r2.y), n3 = __int_as_float(r3.y);
        float n4 = __int_as_float(r4.y), n5 = __int_as_float(r5.y);
        float n6 = __int_as_float(r6.y), n7 = __int_as_float(r7.y);
        a0 += n0 * w0.x; a1 += n0 * w0.y;
        a0 += n1 * w1.x; a1 += n1 * w1.y;
        a0 += n2 * w2.x; a1 += n2 * w2.y;
        a0 += n3 * w3.x; a1 += n3 * w3.y;
        a0 += n4 * w4.x; a1 += n4 * w4.y;
        a0 += n5 * w5.x; a1 += n5 * w5.y;
        a0 += n6 * w6.x; a1 += n6 * w6.y;
        a0 += n7 * w7.x; a1 += n7 * w7.y;
    }
    for (; e < e1; e++) {
        int2 r = ebuf[e];
        float nm = __int_as_float(r.y);
        float2 w = __half22float2(tp[(size_t)r.x * 64 + f]);
        a0 += nm * w.x; a1 += nm * w.y;
    }
    float2 b = ((const float2*)bias)[f];
    a0 += b.x; a1 += b.y;
    if (relu) { a0 = fmaxf(a0, 0.f); a1 = fmaxf(a1, 0.f); }
    ((float2*)out)[(size_t)i * 64 + f] = make_float2(a0, a1);
}

// conv3 aggregation: row for edge src is zz[bg] where ebuf2 = {bg, norm}; zz L2-resident
__global__ __launch_bounds__(64) void agg_out_k(const float* __restrict__ zz,
                                                const int* __restrict__ batch,
                                                const int* __restrict__ rowptr,
                                                const int2* __restrict__ ebuf2,
                                                const float* __restrict__ dinv,
                                                const float* __restrict__ bias,
                                                float* __restrict__ out)
{
    int i = blockIdx.x;
    int f = threadIdx.x;
    const float2* zp = (const float2*)zz;
    float di = dinv[i];
    float sn = di * di;
    float2 v = zp[(size_t)batch[i] * 64 + f];
    float a0 = sn * v.x, a1 = sn * v.y;
    int e0 = rowptr[i], e1 = rowptr[i + 1];
    int e = e0;
    for (; e + 3 < e1; e += 4) {
        int2 r0 = ebuf2[e],     r1 = ebuf2[e + 1];
        int2 r2 = ebuf2[e + 2], r3 = ebuf2[e + 3];
        float2 w0 = zp[(size_t)r0.x * 64 + f];
        float2 w1 = zp[(size_t)r1.x * 64 + f];
        float2 w2 = zp[(size_t)r2.x * 64 + f];
        float2 w3 = zp[(size_t)r3.x * 64 + f];
        float n0 = __int_as_float(r0.y), n1 = __int_as_float(r1.y);
        float n2 = __int_as_float(r2.y), n3 = __int_as_float(r3.y);
        a0 += n0 * w0.x; a1 += n0 * w0.y;
        a0 += n1 * w1.x; a1 += n1 * w1.y;
        a0 += n2 * w2.x; a1 += n2 * w2.y;
        a0 += n3 * w3.x; a1 += n3 * w3.y;
    }
    for (; e < e1; e++) {
        int2 r = ebuf2[e];
        float nm = __int_as_float(r.y);
        float2 w = zp[(size_t)r.x * 64 + f];
        a0 += nm * w.x; a1 += nm * w.y;
    }
    float2 b = ((const float2*)bias)[f];
    a0 += b.x; a1 += b.y;
    ((float2*)out)[(size_t)i * 64 + f] = make_float2(a0, a1);
}

// ---------- pooling (parallel): pooled[g][f] += partial sums over chunk c of graph g ----------
__global__ __launch_bounds__(128) void pool2_k(const float* __restrict__ h2,
                                               const int* __restrict__ batch,
                                               float* __restrict__ pooled)
{
    int g = blockIdx.x;
    int c = blockIdx.y;
    int f = threadIdx.x;
    int bs = lowerb(batch, NN, g);
    int be = lowerb(batch, NN, g + 1);
    int len = be - bs;
    int cs = bs + (int)(((long long)len * c) / PCH);
    int ce = bs + (int)(((long long)len * (c + 1)) / PCH);
    float a = 0.f;
    for (int i = cs; i < ce; i++) a += h2[(size_t)i * 128 + f];
    if (ce > cs) atomicAdd(&pooled[(size_t)g * 128 + f], a);
}

// ---------- fc: latent = relu(pooled @ fcW + fcb); writes latent to d_out too ----------
__global__ __launch_bounds__(64) void fc_k(const float* __restrict__ pooled,
                                           const float* __restrict__ fcW,    // [128][64]
                                           const float* __restrict__ fcb,
                                           float* __restrict__ latentf,
                                           float* __restrict__ lat_out)
{
    int g = blockIdx.x, l = threadIdx.x;
    const float* p = pooled + (size_t)g * 128;
    float a = fcb[l];
    #pragma unroll 8
    for (int k = 0; k < 128; k++) a = fmaf(p[k], fcW[(size_t)k * 64 + l], a);
    a = fmaxf(a, 0.f);
    latentf[(size_t)g * 64 + l] = a;
    lat_out[(size_t)g * 64 + l] = a;
}

// ---------- decoder + W3 transform: zz = relu(latent@decW + decb) @ W3 ----------
__global__ __launch_bounds__(128) void dec_k(const float* __restrict__ latentf,
                                             const float* __restrict__ decW,  // [64][128]
                                             const float* __restrict__ decb,
                                             const float* __restrict__ W3,    // [128][128]
                                             float* __restrict__ zz)
{
    __shared__ float zs[128];
    int g = blockIdx.x, c = threadIdx.x;
    const float* lat = latentf + (size_t)g * 64;
    {
        float a = decb[c];
        #pragma unroll 8
        for (int k = 0; k < 64; k++) a = fmaf(lat[k], decW[(size_t)k * 128 + c], a);
        zs[c] = fmaxf(a, 0.f);
    }
    __syncthreads();
    float o = 0.f;
    #pragma unroll 8
    for (int k = 0; k < 128; k++) o = fmaf(zs[k], W3[(size_t)k * 128 + c], o);
    zz[(size_t)g * 128 + c] = o;
}

extern "C" void kernel_launch(void* const* d_in, const int* in_sizes, int n_in,
                              void* d_out, int out_size, void* d_ws, size_t ws_size,
                              hipStream_t stream)
{
    const float* x     = (const float*)d_in[0];
    const int*   ei    = (const int*)d_in[1];
    const int*   batch = (const int*)d_in[2];
    const float* W1  = (const float*)d_in[3];
    const float* b1  = (const float*)d_in[4];
    const float* W2  = (const float*)d_in[5];
    const float* b2  = (const float*)d_in[6];
    const float* fcW = (const float*)d_in[7];
    const float* fcb = (const float*)d_in[8];
    const float* decW= (const float*)d_in[9];
    const float* decb= (const float*)d_in[10];
    const float* W3  = (const float*)d_in[11];
    const float* b3  = (const float*)d_in[12];

    char* ws = (char*)d_ws;
    size_t off = 0;
    auto alloc = [&](size_t bytes) -> char* {
        char* p = ws + off;
        off = (off + bytes + 255) & ~(size_t)255;
        return p;
    };
    float* dinv     = (float*)alloc((size_t)NN * 4);
    int*   cnt      = (int*)alloc((size_t)NN * 4);
    int*   rowptr   = (int*)alloc((size_t)(NN + 1) * 4);
    int*   bcur     = (int*)alloc((size_t)NB * 4);
    int*   bsum     = (int*)alloc((size_t)NBLK * 4);
    int*   boff     = (int*)alloc(256 * 4);
    int2*  ebuf     = (int2*)alloc((size_t)EE * 8);          // final CSR records {src, norm}
    float* pooled   = (float*)alloc((size_t)GG * 128 * 4);
    float* latentf  = (float*)alloc((size_t)GG * 64 * 4);
    float* zz       = (float*)alloc((size_t)GG * 128 * 4);
    __half* A       = (__half*)alloc((size_t)NN * 128 * 2);  // transformed features t (fp16)
    float* B        = (float*)alloc((size_t)NN * 128 * 4);   // hidden activations h (f32)
    // aliases: eraw (pass-A output, 6.4MB) lives in B (consumed before aggh1 writes B);
    // ebuf2 lives in A (built after the 2nd aggh has consumed A)
    int2*  eraw     = (int2*)B;
    int2*  ebuf2    = (int2*)A;

    float* recon_out = (float*)d_out;
    float* lat_out   = (float*)d_out + (size_t)NN * 128;

    hipMemsetAsync(cnt, 0, (size_t)NN * 4, stream);
    hipMemsetAsync(pooled, 0, (size_t)GG * 128 * 4, stream);
    count_k<<<(EE + 255) / 256, 256, 0, stream>>>(ei, cnt);
    bsum_k<<<NBLK, 256, 0, stream>>>(cnt, bsum);
    scanb_k<<<1, 256, 0, stream>>>(bsum, boff);
    emit_k<<<NBLK, 256, 0, stream>>>(cnt, boff, rowptr, bcur, dinv);
    binA_k<<<ABLK, 256, 0, stream>>>(ei, bcur, eraw);
    binB_k<<<NB, 256, 0, stream>>>(eraw, rowptr, dinv, ebuf);

    dim3 ggrid((NN + 255) / 256, 8);
    // conv1: t1 = x @ W1 -> A (fp16) ; h1 = relu(agg(A) + b1) -> B
    gemm128h_k<<<ggrid, 256, 0, stream>>>(x, W1, A, NN);
    aggh_k<<<NN, 64, 0, stream>>>(A, rowptr, ebuf, dinv, b1, B, 1);
    // conv2: t2 = h1 @ W2 -> A (fp16) ; h2 = relu(agg(A) + b2) -> B
    gemm128h_k<<<ggrid, 256, 0, stream>>>(B, W2, A, NN);
    aggh_k<<<NN, 64, 0, stream>>>(A, rowptr, ebuf, dinv, b2, B, 1);
    // A is now free -> build ebuf2 in its space
    pb_k<<<(EE + 255) / 256, 256, 0, stream>>>(ebuf, batch, ebuf2);
    // pool + fc (latent out) + decoder(+W3 transform)
    pool2_k<<<dim3(GG, PCH), 128, 0, stream>>>(B, batch, pooled);
    fc_k<<<GG, 64, 0, stream>>>(pooled, fcW, fcb, latentf, lat_out);
    dec_k<<<GG, 128, 0, stream>>>(latentf, decW, decb, W3, zz);
    // conv3 -> recon
    agg_out_k<<<NN, 64, 0, stream>>>(zz, batch, rowptr, ebuf2, dinv,
                                     b3, recon_out);
}

// Round 4
// 324.955 us; speedup vs baseline: 1.3182x; 1.1259x over previous
//
#include <hip/hip_runtime.h>
#include <hip/hip_fp16.h>

// Problem constants
static constexpr int NN   = 50000;
static constexpr int EE   = 800000;
static constexpr int GG   = 256;
static constexpr int PCH  = 16;                 // pooling chunks per graph
static constexpr int BK   = 128;                // targets per bucket
static constexpr int NB   = (NN + BK - 1) / BK; // 391 buckets (bucket = dst>>7)
static constexpr int CAP  = 4096;               // bucket region capacity (mean 2048, sigma 45)
static constexpr int CH   = 2048;               // edges per binA block
static constexpr int ABLK = (EE + CH - 1) / CH; // 391

// ---------- helpers ----------
__device__ __forceinline__ int lowerb(const int* __restrict__ b, int n, int v) {
    int lo = 0, hi = n;
    while (lo < hi) { int m = (lo + hi) >> 1; if (b[m] < v) lo = m + 1; else hi = m; }
    return lo;
}

// ---------- CSR build ----------
// init bucket write cursors to fixed region starts
__global__ void init_k(int* __restrict__ bcur)
{
    int b = blockIdx.x * 256 + threadIdx.x;
    if (b < NB) bcur[b] = b * CAP;
}

// Pass A: partition edges into fixed-capacity bucket regions, coalesced flush.
// 391 blocks x 512 threads; per-block LDS histogram + parallel scan + regroup.
__global__ __launch_bounds__(512) void binA_k(const int* __restrict__ ei,
                                              int* __restrict__ bcur,
                                              int2* __restrict__ eraw)
{
    __shared__ int2  stage[CH];
    __shared__ short sbid[CH];
    __shared__ int   hist[NB], loff[NB], gbase[NB], lcur[NB];
    __shared__ int   sc[512];

    int tid = threadIdx.x;
    int e0 = blockIdx.x * CH;
    int n = EE - e0; if (n > CH) n = CH;

    for (int b = tid; b < NB; b += 512) hist[b] = 0;
    __syncthreads();

    int2 r[CH / 512];
    #pragma unroll
    for (int k = 0; k < CH / 512; k++) {
        int s = k * 512 + tid;
        if (s < n) {
            int src = ei[e0 + s];
            int dst = ei[EE + e0 + s];
            r[k] = make_int2(src, dst);
            atomicAdd(&hist[dst >> 7], 1);
        }
    }
    __syncthreads();
    // parallel exclusive scan of hist[0..NB) (NB=391 <= 512)
    int v = (tid < NB) ? hist[tid] : 0;
    sc[tid] = v;
    __syncthreads();
    #pragma unroll
    for (int off = 1; off < 512; off <<= 1) {
        int add = (tid >= off) ? sc[tid - off] : 0;
        __syncthreads();
        sc[tid] += add;
        __syncthreads();
    }
    if (tid < NB) { int ex = sc[tid] - v; loff[tid] = ex; lcur[tid] = ex; }
    __syncthreads();
    for (int b = tid; b < NB; b += 512)
        gbase[b] = atomicAdd(&bcur[b], hist[b]);
    __syncthreads();
    #pragma unroll
    for (int k = 0; k < CH / 512; k++) {
        int s = k * 512 + tid;
        if (s < n) {
            int b = r[k].y >> 7;
            int slot = atomicAdd(&lcur[b], 1);
            stage[slot] = r[k];
            sbid[slot]  = (short)b;
        }
    }
    __syncthreads();
    for (int s = tid; s < n; s += 512) {
        int b = sbid[s];
        eraw[(size_t)gbase[b] + (s - loff[b])] = stage[s];   // coalesced per-bucket runs
    }
}

// scan bucket totals -> bucket base offsets (= rowptr at bucket starts); rowptr[NN]=EE
__global__ __launch_bounds__(512) void scanb2_k(const int* __restrict__ bcur,
                                                int* __restrict__ bbase,
                                                int* __restrict__ rowptr)
{
    __shared__ int s[512];
    int t = threadIdx.x;
    int v = (t < NB) ? (bcur[t] - t * CAP) : 0;
    s[t] = v;
    __syncthreads();
    #pragma unroll
    for (int off = 1; off < 512; off <<= 1) {
        int add = (t >= off) ? s[t - off] : 0;
        __syncthreads();
        s[t] += add;
        __syncthreads();
    }
    if (t < NB) bbase[t] = s[t] - v;
    if (t == 0) rowptr[NN] = EE;
}

// Pass B: per bucket (391 blocks x 512 thr): LDS hist of dst&127 -> per-node rowptr,
// then place src ints at exact CSR slots via LDS cursors (writes confined to 16KB window).
__global__ __launch_bounds__(512) void binB_k(const int2* __restrict__ eraw,
                                              const int* __restrict__ bcur,
                                              const int* __restrict__ bbase,
                                              int* __restrict__ rowptr,
                                              int* __restrict__ ebuf)
{
    __shared__ int hist[BK], excl[BK], cur[BK];
    int b = blockIdx.x, tid = threadIdx.x;
    int t0 = b << 7;
    int lim = NN - t0; if (lim > BK) lim = BK;
    int tot  = bcur[b] - b * CAP;
    int base = bbase[b];
    const int2* er = eraw + (size_t)b * CAP;

    if (tid < BK) hist[tid] = 0;
    __syncthreads();
    for (int s = tid; s < tot; s += 512) atomicAdd(&hist[er[s].y & 127], 1);
    __syncthreads();
    if (tid < BK) excl[tid] = hist[tid];
    __syncthreads();
    #pragma unroll
    for (int off = 1; off < BK; off <<= 1) {
        int add = (tid >= off && tid < BK) ? excl[tid - off] : 0;
        __syncthreads();
        if (tid < BK) excl[tid] += add;
        __syncthreads();
    }
    if (tid < BK) {
        int ex = excl[tid] - hist[tid];      // exclusive
        cur[tid] = base + ex;
        if (tid < lim) rowptr[t0 + tid] = base + ex;
    }
    __syncthreads();
    for (int s = tid; s < tot; s += 512) {
        int2 rec = er[s];                    // L2-hot second read
        int p = atomicAdd(&cur[rec.y & 127], 1);
        ebuf[p] = rec.x;
    }
}

// dinv from rowptr degree (+1 self-loop)
__global__ void dinv_k(const int* __restrict__ rowptr, float* __restrict__ dinv)
{
    int i = blockIdx.x * 256 + threadIdx.x;
    if (i < NN) dinv[i] = rsqrtf((float)(rowptr[i + 1] - rowptr[i] + 1));
}

// edge-parallel: ebuf2[e] = {batch[src], dinv[src]} (coalesced stream, L2-resident gathers)
__global__ void pbb_k(const int* __restrict__ ebuf, const int* __restrict__ batch,
                      const float* __restrict__ dinv, int2* __restrict__ ebuf2)
{
    int e = blockIdx.x * 256 + threadIdx.x;
    if (e < EE) {
        int src = ebuf[e];
        ebuf2[e] = make_int2(batch[src], __float_as_int(dinv[src]));
    }
}

// ---------- GEMM: out[r] = dinv[r] * (in[r][:] @ W[:, c0..c0+16)), fp16 output ----------
// 16 cols/thread, gridDim.y=8 -> 6272 waves; input re-reads served by L2/L3
__global__ __launch_bounds__(256) void gemm128h_k(const float* __restrict__ in,
                                                  const float* __restrict__ W,
                                                  const float* __restrict__ dinv,
                                                  __half* __restrict__ out,
                                                  int rows)
{
    int r = blockIdx.x * 256 + threadIdx.x;
    if (r >= rows) return;
    int c0 = blockIdx.y * 16;
    const float* rowp = in + (size_t)r * 128;

    float acc[16];
    #pragma unroll
    for (int j = 0; j < 16; j++) acc[j] = 0.f;

    #pragma unroll 4
    for (int k0 = 0; k0 < 128; k0 += 8) {
        float4 ra = *(const float4*)(rowp + k0);
        float4 rb = *(const float4*)(rowp + k0 + 4);
        float rr[8] = {ra.x, ra.y, ra.z, ra.w, rb.x, rb.y, rb.z, rb.w};
        #pragma unroll
        for (int kk = 0; kk < 8; kk++) {
            const float* wr = W + (size_t)(k0 + kk) * 128 + c0;   // wave-uniform -> s_load
            #pragma unroll
            for (int j = 0; j < 16; j++) acc[j] = fmaf(rr[kk], wr[j], acc[j]);
        }
    }
    float sc = dinv[r];
    __half2 hb[8];
    #pragma unroll
    for (int j = 0; j < 16; j += 2) hb[j >> 1] = __floats2half2_rn(acc[j] * sc, acc[j + 1] * sc);
    uint4* op = (uint4*)(out + (size_t)r * 128 + c0);
    const uint4* hp = (const uint4*)hb;
    op[0] = hp[0];
    op[1] = hp[1];
}

// ---------- aggregation (factorized norm): out[i] = relu?( dinv[i]*(sum_e A[src] + A[i]) + b )
// A rows are pre-scaled by dinv[src]; ebuf = plain src ints (4B/edge)
__global__ __launch_bounds__(64) void aggh_k(const __half* __restrict__ t,
                                             const int* __restrict__ rowptr,
                                             const int* __restrict__ ebuf,
                                             const float* __restrict__ dinv,
                                             const float* __restrict__ bias,
                                             float* __restrict__ out,
                                             int relu)
{
    int i = blockIdx.x;
    int f = threadIdx.x;
    const __half2* tp = (const __half2*)t;   // row = 64 half2
    float2 v = __half22float2(tp[(size_t)i * 64 + f]);
    float a0 = v.x, a1 = v.y;                // self term (pre-scaled row)
    int e0 = __builtin_amdgcn_readfirstlane(rowptr[i]);
    int e1 = __builtin_amdgcn_readfirstlane(rowptr[i + 1]);
    int e = e0;
    for (; e + 7 < e1; e += 8) {
        int s0 = ebuf[e],     s1 = ebuf[e + 1];
        int s2 = ebuf[e + 2], s3 = ebuf[e + 3];
        int s4 = ebuf[e + 4], s5 = ebuf[e + 5];
        int s6 = ebuf[e + 6], s7 = ebuf[e + 7];
        float2 w0 = __half22float2(tp[(size_t)s0 * 64 + f]);
        float2 w1 = __half22float2(tp[(size_t)s1 * 64 + f]);
        float2 w2 = __half22float2(tp[(size_t)s2 * 64 + f]);
        float2 w3 = __half22float2(tp[(size_t)s3 * 64 + f]);
        float2 w4 = __half22float2(tp[(size_t)s4 * 64 + f]);
        float2 w5 = __half22float2(tp[(size_t)s5 * 64 + f]);
        float2 w6 = __half22float2(tp[(size_t)s6 * 64 + f]);
        float2 w7 = __half22float2(tp[(size_t)s7 * 64 + f]);
        a0 += w0.x + w1.x + w2.x + w3.x + w4.x + w5.x + w6.x + w7.x;
        a1 += w0.y + w1.y + w2.y + w3.y + w4.y + w5.y + w6.y + w7.y;
    }
    for (; e < e1; e++) {
        float2 w = __half22float2(tp[(size_t)ebuf[e] * 64 + f]);
        a0 += w.x; a1 += w.y;
    }
    float di = dinv[i];
    float2 b = ((const float2*)bias)[f];
    a0 = di * a0 + b.x;
    a1 = di * a1 + b.y;
    if (relu) { a0 = fmaxf(a0, 0.f); a1 = fmaxf(a1, 0.f); }
    ((float2*)out)[(size_t)i * 64 + f] = make_float2(a0, a1);
}

// conv3 aggregation: ebuf2 = {bg, w=dinv[src]}; zz L2-resident
// out[i] = dinv[i]*( dinv[i]*zz[batch[i]] + sum_e w_e*zz[bg_e] ) + b
__global__ __launch_bounds__(64) void agg_out_k(const float* __restrict__ zz,
                                                const int* __restrict__ batch,
                                                const int* __restrict__ rowptr,
                                                const int2* __restrict__ ebuf2,
                                                const float* __restrict__ dinv,
                                                const float* __restrict__ bias,
                                                float* __restrict__ out)
{
    int i = blockIdx.x;
    int f = threadIdx.x;
    const float2* zp = (const float2*)zz;
    float di = dinv[i];
    float2 v = zp[(size_t)batch[i] * 64 + f];
    float a0 = di * v.x, a1 = di * v.y;
    int e0 = rowptr[i], e1 = rowptr[i + 1];
    int e = e0;
    for (; e + 3 < e1; e += 4) {
        int2 r0 = ebuf2[e],     r1 = ebuf2[e + 1];
        int2 r2 = ebuf2[e + 2], r3 = ebuf2[e + 3];
        float2 w0 = zp[(size_t)r0.x * 64 + f];
        float2 w1 = zp[(size_t)r1.x * 64 + f];
        float2 w2 = zp[(size_t)r2.x * 64 + f];
        float2 w3 = zp[(size_t)r3.x * 64 + f];
        float n0 = __int_as_float(r0.y), n1 = __int_as_float(r1.y);
        float n2 = __int_as_float(r2.y), n3 = __int_as_float(r3.y);
        a0 += n0 * w0.x; a1 += n0 * w0.y;
        a0 += n1 * w1.x; a1 += n1 * w1.y;
        a0 += n2 * w2.x; a1 += n2 * w2.y;
        a0 += n3 * w3.x; a1 += n3 * w3.y;
    }
    for (; e < e1; e++) {
        int2 r = ebuf2[e];
        float nm = __int_as_float(r.y);
        float2 w = zp[(size_t)r.x * 64 + f];
        a0 += nm * w.x; a1 += nm * w.y;
    }
    float2 b = ((const float2*)bias)[f];
    a0 = di * a0 + b.x;
    a1 = di * a1 + b.y;
    ((float2*)out)[(size_t)i * 64 + f] = make_float2(a0, a1);
}

// ---------- pooling (parallel): pooled[g][f] += partial sums over chunk c of graph g ----------
__global__ __launch_bounds__(128) void pool2_k(const float* __restrict__ h2,
                                               const int* __restrict__ batch,
                                               float* __restrict__ pooled)
{
    int g = blockIdx.x;
    int c = blockIdx.y;
    int f = threadIdx.x;
    int bs = lowerb(batch, NN, g);
    int be = lowerb(batch, NN, g + 1);
    int len = be - bs;
    int cs = bs + (int)(((long long)len * c) / PCH);
    int ce = bs + (int)(((long long)len * (c + 1)) / PCH);
    float a = 0.f;
    for (int i = cs; i < ce; i++) a += h2[(size_t)i * 128 + f];
    if (ce > cs) atomicAdd(&pooled[(size_t)g * 128 + f], a);
}

// ---------- fc: latent = relu(pooled @ fcW + fcb); writes latent to d_out too ----------
__global__ __launch_bounds__(64) void fc_k(const float* __restrict__ pooled,
                                           const float* __restrict__ fcW,    // [128][64]
                                           const float* __restrict__ fcb,
                                           float* __restrict__ latentf,
                                           float* __restrict__ lat_out)
{
    int g = blockIdx.x, l = threadIdx.x;
    const float* p = pooled + (size_t)g * 128;
    float a = fcb[l];
    #pragma unroll 8
    for (int k = 0; k < 128; k++) a = fmaf(p[k], fcW[(size_t)k * 64 + l], a);
    a = fmaxf(a, 0.f);
    latentf[(size_t)g * 64 + l] = a;
    lat_out[(size_t)g * 64 + l] = a;
}

// ---------- decoder + W3 transform: zz = relu(latent@decW + decb) @ W3 ----------
__global__ __launch_bounds__(128) void dec_k(const float* __restrict__ latentf,
                                             const float* __restrict__ decW,  // [64][128]
                                             const float* __restrict__ decb,
                                             const float* __restrict__ W3,    // [128][128]
                                             float* __restrict__ zz)
{
    __shared__ float zs[128];
    int g = blockIdx.x, c = threadIdx.x;
    const float* lat = latentf + (size_t)g * 64;
    {
        float a = decb[c];
        #pragma unroll 8
        for (int k = 0; k < 64; k++) a = fmaf(lat[k], decW[(size_t)k * 128 + c], a);
        zs[c] = fmaxf(a, 0.f);
    }
    __syncthreads();
    float o = 0.f;
    #pragma unroll 8
    for (int k = 0; k < 128; k++) o = fmaf(zs[k], W3[(size_t)k * 128 + c], o);
    zz[(size_t)g * 128 + c] = o;
}

extern "C" void kernel_launch(void* const* d_in, const int* in_sizes, int n_in,
                              void* d_out, int out_size, void* d_ws, size_t ws_size,
                              hipStream_t stream)
{
    const float* x     = (const float*)d_in[0];
    const int*   ei    = (const int*)d_in[1];
    const int*   batch = (const int*)d_in[2];
    const float* W1  = (const float*)d_in[3];
    const float* b1  = (const float*)d_in[4];
    const float* W2  = (const float*)d_in[5];
    const float* b2  = (const float*)d_in[6];
    const float* fcW = (const float*)d_in[7];
    const float* fcb = (const float*)d_in[8];
    const float* decW= (const float*)d_in[9];
    const float* decb= (const float*)d_in[10];
    const float* W3  = (const float*)d_in[11];
    const float* b3  = (const float*)d_in[12];

    char* ws = (char*)d_ws;
    size_t off = 0;
    auto alloc = [&](size_t bytes) -> char* {
        char* p = ws + off;
        off = (off + bytes + 255) & ~(size_t)255;
        return p;
    };
    float* dinv     = (float*)alloc((size_t)NN * 4);
    int*   rowptr   = (int*)alloc((size_t)(NN + 1) * 4);
    int*   bcur     = (int*)alloc((size_t)NB * 4);
    int*   bbase    = (int*)alloc((size_t)NB * 4);
    int*   ebuf     = (int*)alloc((size_t)EE * 4);           // CSR src indices (4B/edge)
    float* pooled   = (float*)alloc((size_t)GG * 128 * 4);
    float* latentf  = (float*)alloc((size_t)GG * 64 * 4);
    float* zz       = (float*)alloc((size_t)GG * 128 * 4);
    __half* A       = (__half*)alloc((size_t)NN * 128 * 2);  // pre-scaled transformed feats (fp16)
    float* B        = (float*)alloc((size_t)NN * 128 * 4);   // hidden activations h (f32)
    // aliases: eraw (12.81MB) in B (25.6MB, consumed before aggh1 writes B);
    // ebuf2 (6.4MB) in A (12.8MB, built after aggh2 has consumed A)
    int2*  eraw     = (int2*)B;
    int2*  ebuf2    = (int2*)A;

    float* recon_out = (float*)d_out;
    float* lat_out   = (float*)d_out + (size_t)NN * 128;

    hipMemsetAsync(pooled, 0, (size_t)GG * 128 * 4, stream);
    init_k<<<(NB + 255) / 256, 256, 0, stream>>>(bcur);
    binA_k<<<ABLK, 512, 0, stream>>>(ei, bcur, eraw);
    scanb2_k<<<1, 512, 0, stream>>>(bcur, bbase, rowptr);
    binB_k<<<NB, 512, 0, stream>>>(eraw, bcur, bbase, rowptr, ebuf);
    dinv_k<<<(NN + 255) / 256, 256, 0, stream>>>(rowptr, dinv);

    dim3 ggrid((NN + 255) / 256, 8);
    // conv1: A = dinv .* (x @ W1) (fp16) ; h1 = relu(dinv.*(agg(A)) + b1) -> B
    gemm128h_k<<<ggrid, 256, 0, stream>>>(x, W1, dinv, A, NN);
    aggh_k<<<NN, 64, 0, stream>>>(A, rowptr, ebuf, dinv, b1, B, 1);
    // conv2
    gemm128h_k<<<ggrid, 256, 0, stream>>>(B, W2, dinv, A, NN);
    aggh_k<<<NN, 64, 0, stream>>>(A, rowptr, ebuf, dinv, b2, B, 1);
    // A free -> build ebuf2 {batch[src], dinv[src]}
    pbb_k<<<(EE + 255) / 256, 256, 0, stream>>>(ebuf, batch, dinv, ebuf2);
    // pool + fc (latent out) + decoder(+W3 transform)
    pool2_k<<<dim3(GG, PCH), 128, 0, stream>>>(B, batch, pooled);
    fc_k<<<GG, 64, 0, stream>>>(pooled, fcW, fcb, latentf, lat_out);
    dec_k<<<GG, 128, 0, stream>>>(latentf, decW, decb, W3, zz);
    // conv3 -> recon
    agg_out_k<<<NN, 64, 0, stream>>>(zz, batch, rowptr, ebuf2, dinv,
                                     b3, recon_out);
}

// Round 5
// 293.529 us; speedup vs baseline: 1.4593x; 1.1071x over previous
//
#include <hip/hip_runtime.h>
#include <hip/hip_fp16.h>

// Problem constants
static constexpr int NN   = 50000;
static constexpr int EE   = 800000;
static constexpr int GG   = 256;
static constexpr int PCH  = 16;                 // pooling chunks per graph
static constexpr int BK   = 128;                // targets per bucket
static constexpr int NB   = (NN + BK - 1) / BK; // 391 buckets (bucket = dst>>7)
static constexpr int CAP  = 4096;               // bucket region capacity (mean 2048, sigma 45)
static constexpr int CH   = 2048;               // edges per binA block
static constexpr int ABLK = (EE + CH - 1) / CH; // 391

typedef _Float16 f16;
typedef f16  f16x8 __attribute__((ext_vector_type(8)));
typedef float f32x4 __attribute__((ext_vector_type(4)));

// ---------- helpers ----------
__device__ __forceinline__ int lowerb(const int* __restrict__ b, int n, int v) {
    int lo = 0, hi = n;
    while (lo < hi) { int m = (lo + hi) >> 1; if (b[m] < v) lo = m + 1; else hi = m; }
    return lo;
}

// ---------- CSR build ----------
// init bucket write cursors to fixed region starts
__global__ void init_k(int* __restrict__ bcur)
{
    int b = blockIdx.x * 256 + threadIdx.x;
    if (b < NB) bcur[b] = b * CAP;
}

// Pass A: partition edges into fixed-capacity bucket regions, coalesced flush.
__global__ __launch_bounds__(512) void binA_k(const int* __restrict__ ei,
                                              int* __restrict__ bcur,
                                              int2* __restrict__ eraw)
{
    __shared__ int2  stage[CH];
    __shared__ short sbid[CH];
    __shared__ int   hist[NB], loff[NB], gbase[NB], lcur[NB];
    __shared__ int   sc[512];

    int tid = threadIdx.x;
    int e0 = blockIdx.x * CH;
    int n = EE - e0; if (n > CH) n = CH;

    for (int b = tid; b < NB; b += 512) hist[b] = 0;
    __syncthreads();

    int2 r[CH / 512];
    #pragma unroll
    for (int k = 0; k < CH / 512; k++) {
        int s = k * 512 + tid;
        if (s < n) {
            int src = ei[e0 + s];
            int dst = ei[EE + e0 + s];
            r[k] = make_int2(src, dst);
            atomicAdd(&hist[dst >> 7], 1);
        }
    }
    __syncthreads();
    int v = (tid < NB) ? hist[tid] : 0;
    sc[tid] = v;
    __syncthreads();
    #pragma unroll
    for (int off = 1; off < 512; off <<= 1) {
        int add = (tid >= off) ? sc[tid - off] : 0;
        __syncthreads();
        sc[tid] += add;
        __syncthreads();
    }
    if (tid < NB) { int ex = sc[tid] - v; loff[tid] = ex; lcur[tid] = ex; }
    __syncthreads();
    for (int b = tid; b < NB; b += 512)
        gbase[b] = atomicAdd(&bcur[b], hist[b]);
    __syncthreads();
    #pragma unroll
    for (int k = 0; k < CH / 512; k++) {
        int s = k * 512 + tid;
        if (s < n) {
            int b = r[k].y >> 7;
            int slot = atomicAdd(&lcur[b], 1);
            stage[slot] = r[k];
            sbid[slot]  = (short)b;
        }
    }
    __syncthreads();
    for (int s = tid; s < n; s += 512) {
        int b = sbid[s];
        eraw[(size_t)gbase[b] + (s - loff[b])] = stage[s];
    }
}

// scan bucket totals -> bucket base offsets; rowptr[NN]=EE
__global__ __launch_bounds__(512) void scanb2_k(const int* __restrict__ bcur,
                                                int* __restrict__ bbase,
                                                int* __restrict__ rowptr)
{
    __shared__ int s[512];
    int t = threadIdx.x;
    int v = (t < NB) ? (bcur[t] - t * CAP) : 0;
    s[t] = v;
    __syncthreads();
    #pragma unroll
    for (int off = 1; off < 512; off <<= 1) {
        int add = (t >= off) ? s[t - off] : 0;
        __syncthreads();
        s[t] += add;
        __syncthreads();
    }
    if (t < NB) bbase[t] = s[t] - v;
    if (t == 0) rowptr[NN] = EE;
}

// Pass B: per bucket: LDS hist -> rowptr, place src ints at exact CSR slots
__global__ __launch_bounds__(512) void binB_k(const int2* __restrict__ eraw,
                                              const int* __restrict__ bcur,
                                              const int* __restrict__ bbase,
                                              int* __restrict__ rowptr,
                                              int* __restrict__ ebuf)
{
    __shared__ int hist[BK], excl[BK], cur[BK];
    int b = blockIdx.x, tid = threadIdx.x;
    int t0 = b << 7;
    int lim = NN - t0; if (lim > BK) lim = BK;
    int tot  = bcur[b] - b * CAP;
    int base = bbase[b];
    const int2* er = eraw + (size_t)b * CAP;

    if (tid < BK) hist[tid] = 0;
    __syncthreads();
    for (int s = tid; s < tot; s += 512) atomicAdd(&hist[er[s].y & 127], 1);
    __syncthreads();
    if (tid < BK) excl[tid] = hist[tid];
    __syncthreads();
    #pragma unroll
    for (int off = 1; off < BK; off <<= 1) {
        int add = (tid >= off && tid < BK) ? excl[tid - off] : 0;
        __syncthreads();
        if (tid < BK) excl[tid] += add;
        __syncthreads();
    }
    if (tid < BK) {
        int ex = excl[tid] - hist[tid];
        cur[tid] = base + ex;
        if (tid < lim) rowptr[t0 + tid] = base + ex;
    }
    __syncthreads();
    for (int s = tid; s < tot; s += 512) {
        int2 rec = er[s];
        int p = atomicAdd(&cur[rec.y & 127], 1);
        ebuf[p] = rec.x;
    }
}

// dinv from rowptr degree (+1 self-loop)
__global__ void dinv_k(const int* __restrict__ rowptr, float* __restrict__ dinv)
{
    int i = blockIdx.x * 256 + threadIdx.x;
    if (i < NN) dinv[i] = rsqrtf((float)(rowptr[i + 1] - rowptr[i] + 1));
}

// edge-parallel: ebuf2[e] = {batch[src], dinv[src]}
__global__ void pbb_k(const int* __restrict__ ebuf, const int* __restrict__ batch,
                      const float* __restrict__ dinv, int2* __restrict__ ebuf2)
{
    int e = blockIdx.x * 256 + threadIdx.x;
    if (e < EE) {
        int src = ebuf[e];
        ebuf2[e] = make_int2(batch[src], __float_as_int(dinv[src]));
    }
}

// ---------- MFMA GEMM: out = dinv .* (in @ W), fp16 output, split-precision f16 ----------
// Block: 64 rows x 128 cols, 4 waves (16 rows each). W^T staged in LDS as f16 hi/lo
// (XOR-swizzled). t = hi@Whi + lo@Whi + hi@Wlo  => ~f32 accuracy.
// Fragment maps: A: m=lane&15, k=(lane>>4)*8+[0..8) per 32-k step (same formula for B's k
// => any k-permutation error cancels). C/D: col=lane&15, row=(lane>>4)*4+reg (HW-verified).
__global__ __launch_bounds__(256) void gemm_mfma_k(const float* __restrict__ in,
                                                   const float* __restrict__ W,
                                                   const float* __restrict__ dinv,
                                                   __half* __restrict__ out,
                                                   int rows)
{
    __shared__ __align__(16) f16 whi[128 * 128];
    __shared__ __align__(16) f16 wlo[128 * 128];

    int tid = threadIdx.x;
    // ---- stage W^T (col n, k-major) as hi/lo, swizzle byte^=((n&7)<<4) ----
    {
        int n  = tid & 127;
        int kh = tid >> 7;                 // 0/1 -> k half
        int sw = (n & 7) << 4;
        #pragma unroll
        for (int jb = 0; jb < 8; jb++) {   // 8 blocks of 8 k each
            f16x8 h8, l8;
            #pragma unroll
            for (int u = 0; u < 8; u++) {
                int k = kh * 64 + jb * 8 + u;
                float x = W[k * 128 + n];  // coalesced: lanes -> consecutive n
                f16 h = (f16)x;
                h8[u] = h;
                l8[u] = (f16)(x - (float)h);
            }
            int boff = n * 256 + ((kh * 128 + jb * 16) ^ sw);
            *(f16x8*)((char*)whi + boff) = h8;
            *(f16x8*)((char*)wlo + boff) = l8;
        }
    }
    __syncthreads();

    int lane = tid & 63;
    int wv   = tid >> 6;
    int rB   = blockIdx.x * 64 + wv * 16;
    int m    = lane & 15;
    int kq   = lane >> 4;                  // 0..3
    int r    = rB + m;
    int rr   = (r < rows) ? r : (rows - 1);

    // A-frags: k = ks*32 + kq*8 + [0..8)
    f16x8 ahi[4], alo[4];
    const float* rp = in + (size_t)rr * 128 + kq * 8;
    #pragma unroll
    for (int ks = 0; ks < 4; ks++) {
        float4 p0 = *(const float4*)(rp + ks * 32);
        float4 p1 = *(const float4*)(rp + ks * 32 + 4);
        float xs[8] = {p0.x, p0.y, p0.z, p0.w, p1.x, p1.y, p1.z, p1.w};
        #pragma unroll
        for (int u = 0; u < 8; u++) {
            f16 h = (f16)xs[u];
            ahi[ks][u] = h;
            alo[ks][u] = (f16)(xs[u] - (float)h);
        }
    }

    f32x4 acc[8];
    #pragma unroll
    for (int n = 0; n < 8; n++) acc[n] = (f32x4){0.f, 0.f, 0.f, 0.f};

    #pragma unroll
    for (int nt = 0; nt < 8; nt++) {
        int nb   = nt * 16 + m;            // absolute col of this lane's B frag
        int sw   = (nb & 7) << 4;
        int rowb = nb * 256;
        #pragma unroll
        for (int ks = 0; ks < 4; ks++) {
            int off = rowb + (((ks * 64) + (kq * 16)) ^ sw);
            f16x8 bh = *(const f16x8*)((const char*)whi + off);
            f16x8 bl = *(const f16x8*)((const char*)wlo + off);
            acc[nt] = __builtin_amdgcn_mfma_f32_16x16x32_f16(ahi[ks], bh, acc[nt], 0, 0, 0);
            acc[nt] = __builtin_amdgcn_mfma_f32_16x16x32_f16(alo[ks], bh, acc[nt], 0, 0, 0);
            acc[nt] = __builtin_amdgcn_mfma_f32_16x16x32_f16(ahi[ks], bl, acc[nt], 0, 0, 0);
        }
    }

    // epilogue: row = kq*4 + reg, col = nt*16 + m; scale by dinv[row], store f16
    int   orow[4];
    float dv[4];
    #pragma unroll
    for (int j = 0; j < 4; j++) {
        int gr = rB + kq * 4 + j;
        orow[j] = gr;
        dv[j]   = (gr < rows) ? dinv[gr] : 0.f;
    }
    #pragma unroll
    for (int nt = 0; nt < 8; nt++) {
        int c = nt * 16 + m;
        #pragma unroll
        for (int j = 0; j < 4; j++) {
            if (orow[j] < rows)
                out[(size_t)orow[j] * 128 + c] = __float2half(acc[nt][j] * dv[j]);
        }
    }
}

// ---------- aggregation (factorized norm): out[i] = relu?( dinv[i]*(sum_e A[src] + A[i]) + b )
__global__ __launch_bounds__(64) void aggh_k(const __half* __restrict__ t,
                                             const int* __restrict__ rowptr,
                                             const int* __restrict__ ebuf,
                                             const float* __restrict__ dinv,
                                             const float* __restrict__ bias,
                                             float* __restrict__ out,
                                             int relu)
{
    int i = blockIdx.x;
    int f = threadIdx.x;
    const __half2* tp = (const __half2*)t;   // row = 64 half2
    float2 v = __half22float2(tp[(size_t)i * 64 + f]);
    float a0 = v.x, a1 = v.y;                // self term (pre-scaled row)
    int e0 = __builtin_amdgcn_readfirstlane(rowptr[i]);
    int e1 = __builtin_amdgcn_readfirstlane(rowptr[i + 1]);
    int e = e0;
    for (; e + 7 < e1; e += 8) {
        int s0 = ebuf[e],     s1 = ebuf[e + 1];
        int s2 = ebuf[e + 2], s3 = ebuf[e + 3];
        int s4 = ebuf[e + 4], s5 = ebuf[e + 5];
        int s6 = ebuf[e + 6], s7 = ebuf[e + 7];
        float2 w0 = __half22float2(tp[(size_t)s0 * 64 + f]);
        float2 w1 = __half22float2(tp[(size_t)s1 * 64 + f]);
        float2 w2 = __half22float2(tp[(size_t)s2 * 64 + f]);
        float2 w3 = __half22float2(tp[(size_t)s3 * 64 + f]);
        float2 w4 = __half22float2(tp[(size_t)s4 * 64 + f]);
        float2 w5 = __half22float2(tp[(size_t)s5 * 64 + f]);
        float2 w6 = __half22float2(tp[(size_t)s6 * 64 + f]);
        float2 w7 = __half22float2(tp[(size_t)s7 * 64 + f]);
        a0 += w0.x + w1.x + w2.x + w3.x + w4.x + w5.x + w6.x + w7.x;
        a1 += w0.y + w1.y + w2.y + w3.y + w4.y + w5.y + w6.y + w7.y;
    }
    for (; e < e1; e++) {
        float2 w = __half22float2(tp[(size_t)ebuf[e] * 64 + f]);
        a0 += w.x; a1 += w.y;
    }
    float di = dinv[i];
    float2 b = ((const float2*)bias)[f];
    a0 = di * a0 + b.x;
    a1 = di * a1 + b.y;
    if (relu) { a0 = fmaxf(a0, 0.f); a1 = fmaxf(a1, 0.f); }
    ((float2*)out)[(size_t)i * 64 + f] = make_float2(a0, a1);
}

// conv3 aggregation: ebuf2 = {bg, w=dinv[src]}; zz L2-resident
__global__ __launch_bounds__(64) void agg_out_k(const float* __restrict__ zz,
                                                const int* __restrict__ batch,
                                                const int* __restrict__ rowptr,
                                                const int2* __restrict__ ebuf2,
                                                const float* __restrict__ dinv,
                                                const float* __restrict__ bias,
                                                float* __restrict__ out)
{
    int i = blockIdx.x;
    int f = threadIdx.x;
    const float2* zp = (const float2*)zz;
    float di = dinv[i];
    float2 v = zp[(size_t)batch[i] * 64 + f];
    float a0 = di * v.x, a1 = di * v.y;
    int e0 = rowptr[i], e1 = rowptr[i + 1];
    int e = e0;
    for (; e + 3 < e1; e += 4) {
        int2 r0 = ebuf2[e],     r1 = ebuf2[e + 1];
        int2 r2 = ebuf2[e + 2], r3 = ebuf2[e + 3];
        float2 w0 = zp[(size_t)r0.x * 64 + f];
        float2 w1 = zp[(size_t)r1.x * 64 + f];
        float2 w2 = zp[(size_t)r2.x * 64 + f];
        float2 w3 = zp[(size_t)r3.x * 64 + f];
        float n0 = __int_as_float(r0.y), n1 = __int_as_float(r1.y);
        float n2 = __int_as_float(r2.y), n3 = __int_as_float(r3.y);
        a0 += n0 * w0.x; a1 += n0 * w0.y;
        a0 += n1 * w1.x; a1 += n1 * w1.y;
        a0 += n2 * w2.x; a1 += n2 * w2.y;
        a0 += n3 * w3.x; a1 += n3 * w3.y;
    }
    for (; e < e1; e++) {
        int2 r = ebuf2[e];
        float nm = __int_as_float(r.y);
        float2 w = zp[(size_t)r.x * 64 + f];
        a0 += nm * w.x; a1 += nm * w.y;
    }
    float2 b = ((const float2*)bias)[f];
    a0 = di * a0 + b.x;
    a1 = di * a1 + b.y;
    ((float2*)out)[(size_t)i * 64 + f] = make_float2(a0, a1);
}

// ---------- pooling ----------
__global__ __launch_bounds__(128) void pool2_k(const float* __restrict__ h2,
                                               const int* __restrict__ batch,
                                               float* __restrict__ pooled)
{
    int g = blockIdx.x;
    int c = blockIdx.y;
    int f = threadIdx.x;
    int bs = lowerb(batch, NN, g);
    int be = lowerb(batch, NN, g + 1);
    int len = be - bs;
    int cs = bs + (int)(((long long)len * c) / PCH);
    int ce = bs + (int)(((long long)len * (c + 1)) / PCH);
    float a = 0.f;
    for (int i = cs; i < ce; i++) a += h2[(size_t)i * 128 + f];
    if (ce > cs) atomicAdd(&pooled[(size_t)g * 128 + f], a);
}

// ---------- fc ----------
__global__ __launch_bounds__(64) void fc_k(const float* __restrict__ pooled,
                                           const float* __restrict__ fcW,    // [128][64]
                                           const float* __restrict__ fcb,
                                           float* __restrict__ latentf,
                                           float* __restrict__ lat_out)
{
    int g = blockIdx.x, l = threadIdx.x;
    const float* p = pooled + (size_t)g * 128;
    float a = fcb[l];
    #pragma unroll 8
    for (int k = 0; k < 128; k++) a = fmaf(p[k], fcW[(size_t)k * 64 + l], a);
    a = fmaxf(a, 0.f);
    latentf[(size_t)g * 64 + l] = a;
    lat_out[(size_t)g * 64 + l] = a;
}

// ---------- decoder + W3 transform ----------
__global__ __launch_bounds__(128) void dec_k(const float* __restrict__ latentf,
                                             const float* __restrict__ decW,  // [64][128]
                                             const float* __restrict__ decb,
                                             const float* __restrict__ W3,    // [128][128]
                                             float* __restrict__ zz)
{
    __shared__ float zs[128];
    int g = blockIdx.x, c = threadIdx.x;
    const float* lat = latentf + (size_t)g * 64;
    {
        float a = decb[c];
        #pragma unroll 8
        for (int k = 0; k < 64; k++) a = fmaf(lat[k], decW[(size_t)k * 128 + c], a);
        zs[c] = fmaxf(a, 0.f);
    }
    __syncthreads();
    float o = 0.f;
    #pragma unroll 8
    for (int k = 0; k < 128; k++) o = fmaf(zs[k], W3[(size_t)k * 128 + c], o);
    zz[(size_t)g * 128 + c] = o;
}

extern "C" void kernel_launch(void* const* d_in, const int* in_sizes, int n_in,
                              void* d_out, int out_size, void* d_ws, size_t ws_size,
                              hipStream_t stream)
{
    const float* x     = (const float*)d_in[0];
    const int*   ei    = (const int*)d_in[1];
    const int*   batch = (const int*)d_in[2];
    const float* W1  = (const float*)d_in[3];
    const float* b1  = (const float*)d_in[4];
    const float* W2  = (const float*)d_in[5];
    const float* b2  = (const float*)d_in[6];
    const float* fcW = (const float*)d_in[7];
    const float* fcb = (const float*)d_in[8];
    const float* decW= (const float*)d_in[9];
    const float* decb= (const float*)d_in[10];
    const float* W3  = (const float*)d_in[11];
    const float* b3  = (const float*)d_in[12];

    char* ws = (char*)d_ws;
    size_t off = 0;
    auto alloc = [&](size_t bytes) -> char* {
        char* p = ws + off;
        off = (off + bytes + 255) & ~(size_t)255;
        return p;
    };
    float* dinv     = (float*)alloc((size_t)NN * 4);
    int*   rowptr   = (int*)alloc((size_t)(NN + 1) * 4);
    int*   bcur     = (int*)alloc((size_t)NB * 4);
    int*   bbase    = (int*)alloc((size_t)NB * 4);
    int*   ebuf     = (int*)alloc((size_t)EE * 4);           // CSR src indices (4B/edge)
    float* pooled   = (float*)alloc((size_t)GG * 128 * 4);
    float* latentf  = (float*)alloc((size_t)GG * 64 * 4);
    float* zz       = (float*)alloc((size_t)GG * 128 * 4);
    __half* A       = (__half*)alloc((size_t)NN * 128 * 2);  // pre-scaled transformed feats (fp16)
    float* B        = (float*)alloc((size_t)NN * 128 * 4);   // hidden activations h (f32)
    // aliases: eraw (NB*CAP*8 = 12.8MB) in B (25.6MB, consumed before aggh1 writes B);
    // ebuf2 (6.4MB) in A (12.8MB, built after aggh2 has consumed A)
    int2*  eraw     = (int2*)B;
    int2*  ebuf2    = (int2*)A;

    float* recon_out = (float*)d_out;
    float* lat_out   = (float*)d_out + (size_t)NN * 128;

    hipMemsetAsync(pooled, 0, (size_t)GG * 128 * 4, stream);
    init_k<<<(NB + 255) / 256, 256, 0, stream>>>(bcur);
    binA_k<<<ABLK, 512, 0, stream>>>(ei, bcur, eraw);
    scanb2_k<<<1, 512, 0, stream>>>(bcur, bbase, rowptr);
    binB_k<<<NB, 512, 0, stream>>>(eraw, bcur, bbase, rowptr, ebuf);
    dinv_k<<<(NN + 255) / 256, 256, 0, stream>>>(rowptr, dinv);

    int gblk = (NN + 63) / 64;   // 782
    // conv1: A = dinv .* (x @ W1) (fp16) ; h1 = relu(dinv.*(agg(A)) + b1) -> B
    gemm_mfma_k<<<gblk, 256, 0, stream>>>(x, W1, dinv, A, NN);
    aggh_k<<<NN, 64, 0, stream>>>(A, rowptr, ebuf, dinv, b1, B, 1);
    // conv2
    gemm_mfma_k<<<gblk, 256, 0, stream>>>(B, W2, dinv, A, NN);
    aggh_k<<<NN, 64, 0, stream>>>(A, rowptr, ebuf, dinv, b2, B, 1);
    // A free -> build ebuf2 {batch[src], dinv[src]}
    pbb_k<<<(EE + 255) / 256, 256, 0, stream>>>(ebuf, batch, dinv, ebuf2);
    // pool + fc (latent out) + decoder(+W3 transform)
    pool2_k<<<dim3(GG, PCH), 128, 0, stream>>>(B, batch, pooled);
    fc_k<<<GG, 64, 0, stream>>>(pooled, fcW, fcb, latentf, lat_out);
    dec_k<<<GG, 128, 0, stream>>>(latentf, decW, decb, W3, zz);
    // conv3 -> recon
    agg_out_k<<<NN, 64, 0, stream>>>(zz, batch, rowptr, ebuf2, dinv,
                                     b3, recon_out);
}